// Round 1
// baseline (3709.124 us; speedup 1.0000x reference)
//
#include <hip/hip_runtime.h>
#include <math.h>

#define BATCH 2
#define SEQ 4096
#define DIM 512
#define FF 2048
#define NROWS (BATCH*SEQ)
#define RSQRT_D 0.044194173824159216f  /* 1/sqrt(512) */

// ---------------------------------------------------------------- helpers
__device__ __forceinline__ float gelu_f(float v) {
    return 0.5f * v * (1.0f + erff(v * 0.70710678118654752440f));
}

__device__ __forceinline__ float blk_sum256(float v, volatile float* sm) {
    #pragma unroll
    for (int o = 32; o; o >>= 1) v += __shfl_xor(v, o);
    __syncthreads();
    if ((threadIdx.x & 63) == 0) sm[threadIdx.x >> 6] = v;
    __syncthreads();
    return sm[0] + sm[1] + sm[2] + sm[3];
}

// ---------------------------------------------------------------- layernorm
// one wave per row (64 lanes x 8 elems), 4 rows per block
__global__ __launch_bounds__(256) void ln_kernel(const float* __restrict__ x,
        const float* __restrict__ g, const float* __restrict__ be,
        float* __restrict__ o)
{
    int row  = blockIdx.x * 4 + (threadIdx.x >> 6);
    int lane = threadIdx.x & 63;
    const float4* xr = (const float4*)(x + (size_t)row * DIM);
    float4 v0 = xr[lane*2], v1 = xr[lane*2+1];
    float s = v0.x+v0.y+v0.z+v0.w + v1.x+v1.y+v1.z+v1.w;
    #pragma unroll
    for (int off = 32; off; off >>= 1) s += __shfl_xor(s, off);
    float mu = s * (1.0f/DIM);
    float d0=v0.x-mu, d1=v0.y-mu, d2=v0.z-mu, d3=v0.w-mu;
    float d4=v1.x-mu, d5=v1.y-mu, d6=v1.z-mu, d7=v1.w-mu;
    float q = d0*d0+d1*d1+d2*d2+d3*d3+d4*d4+d5*d5+d6*d6+d7*d7;
    #pragma unroll
    for (int off = 32; off; off >>= 1) q += __shfl_xor(q, off);
    float rs = rsqrtf(q * (1.0f/DIM) + 1e-5f);
    const float4* g4 = (const float4*)g;
    const float4* b4 = (const float4*)be;
    float4 ga = g4[lane*2], gb = g4[lane*2+1];
    float4 ba = b4[lane*2], bb = b4[lane*2+1];
    float4 o0, o1;
    o0.x = d0*rs*ga.x + ba.x; o0.y = d1*rs*ga.y + ba.y;
    o0.z = d2*rs*ga.z + ba.z; o0.w = d3*rs*ga.w + ba.w;
    o1.x = d4*rs*gb.x + bb.x; o1.y = d5*rs*gb.y + bb.y;
    o1.z = d6*rs*gb.z + bb.z; o1.w = d7*rs*gb.w + bb.w;
    float4* orow = (float4*)(o + (size_t)row * DIM);
    orow[lane*2] = o0; orow[lane*2+1] = o1;
}

// ---------------------------------------------------------------- SGEMM  C[M,N] (=/+=) A[M,K] * W[N,K]^T (+bias)(gelu)(+res)
// 128x128 block tile, BK=16, 256 threads, 8x8 micro-tile
__global__ __launch_bounds__(256) void sgemm_bt(
        const float* __restrict__ A, const float* __restrict__ W,
        float* __restrict__ C, const float* __restrict__ bias,
        const float* __restrict__ res, int M, int N, int K, int act, int accum)
{
    __shared__ float As[16][132];
    __shared__ float Ws[16][132];
    int tid = threadIdx.x;
    int n0 = blockIdx.x * 128, m0 = blockIdx.y * 128;
    int tx = tid & 15, ty = tid >> 4;
    int lr = tid >> 2;
    int lc = (tid & 3) << 2;
    const float* Ap  = A + (size_t)(m0 + lr) * K + lc;
    const float* Ap2 = Ap + (size_t)64 * K;
    const float* Wp  = W + (size_t)(n0 + lr) * K + lc;
    const float* Wp2 = Wp + (size_t)64 * K;
    float acc[8][8] = {};
    for (int k0 = 0; k0 < K; k0 += 16) {
        float4 a0 = *(const float4*)(Ap  + k0);
        float4 a1 = *(const float4*)(Ap2 + k0);
        float4 w0 = *(const float4*)(Wp  + k0);
        float4 w1 = *(const float4*)(Wp2 + k0);
        __syncthreads();
        As[lc+0][lr]    = a0.x; As[lc+1][lr]    = a0.y; As[lc+2][lr]    = a0.z; As[lc+3][lr]    = a0.w;
        As[lc+0][lr+64] = a1.x; As[lc+1][lr+64] = a1.y; As[lc+2][lr+64] = a1.z; As[lc+3][lr+64] = a1.w;
        Ws[lc+0][lr]    = w0.x; Ws[lc+1][lr]    = w0.y; Ws[lc+2][lr]    = w0.z; Ws[lc+3][lr]    = w0.w;
        Ws[lc+0][lr+64] = w1.x; Ws[lc+1][lr+64] = w1.y; Ws[lc+2][lr+64] = w1.z; Ws[lc+3][lr+64] = w1.w;
        __syncthreads();
        #pragma unroll
        for (int k = 0; k < 16; ++k) {
            float av[8], wv[8];
            *(float4*)&av[0] = *(const float4*)&As[k][ty*8];
            *(float4*)&av[4] = *(const float4*)&As[k][ty*8+4];
            *(float4*)&wv[0] = *(const float4*)&Ws[k][tx*8];
            *(float4*)&wv[4] = *(const float4*)&Ws[k][tx*8+4];
            #pragma unroll
            for (int i = 0; i < 8; ++i)
                #pragma unroll
                for (int j = 0; j < 8; ++j)
                    acc[i][j] = fmaf(av[i], wv[j], acc[i][j]);
        }
    }
    #pragma unroll
    for (int i = 0; i < 8; ++i) {
        size_t m = (size_t)m0 + ty*8 + i;
        #pragma unroll
        for (int j = 0; j < 8; ++j) {
            int n = n0 + tx*8 + j;
            float v = acc[i][j];
            if (bias) v += bias[n];
            if (act)  v = gelu_f(v);
            if (res)  v += res[m * N + n];
            size_t idx = m * N + n;
            if (accum) C[idx] += v; else C[idx] = v;
        }
    }
}

// ---------------------------------------------------------------- flash attention (fp32)
// QT=8 query rows per block, KT=64 keys per tile, 256 threads.
// scores micro: thread owns 1 q-row (tid>>5) and 2 keys (kkg, kkg+32).
// K tile staged in LDS in 128-dim chunks, XOR-swizzled to break bank conflicts.
#define QT 8
#define KT 64
__global__ __launch_bounds__(256) void flash_attn(
        const float* __restrict__ Qp, const float* __restrict__ Kp,
        const float* __restrict__ Vp, float* __restrict__ Op,
        float scale, const float* __restrict__ scale_ptr,
        int causal, int accum, const float* __restrict__ gate)
{
    if (gate && gate[0] == 0.0f) return;
    if (scale_ptr) scale = scale_ptr[0];
    __shared__ float q_s[QT][512];
    __shared__ float k_s[KT][128];
    __shared__ float s_s[QT][KT];
    __shared__ float m_s[QT], l_s[QT], f_s[QT];
    int tid = threadIdx.x;
    int b   = blockIdx.y;
    int q0  = blockIdx.x * QT;
    size_t base = (size_t)b * SEQ * DIM;
    for (int i = tid; i < QT*DIM/4; i += 256) {
        int r = i >> 7, c = (i & 127) << 2;
        *(float4*)&q_s[r][c] = *(const float4*)&Qp[base + (size_t)(q0+r)*DIM + c];
    }
    if (tid < QT) { m_s[tid] = -1e30f; l_s[tid] = 0.0f; }
    float accv[QT][2];
    #pragma unroll
    for (int r = 0; r < QT; ++r) { accv[r][0] = 0.f; accv[r][1] = 0.f; }
    int d0 = tid, d1 = tid + 256;
    int rq  = tid >> 5;          // my q row
    int kkg = tid & 31;          // my keys: kkg, kkg+32
    int kkA = kkg, kkB = kkg + 32;
    int kend = causal ? (q0 + QT) : SEQ;
    for (int k0 = 0; k0 < kend; k0 += KT) {
        float s0 = 0.f, s1 = 0.f;
        for (int dc = 0; dc < 4; ++dc) {
            __syncthreads();
            for (int i = tid; i < KT*128/4; i += 256) {
                int r = i >> 5, c4 = i & 31;
                *(float4*)&k_s[r][(c4 ^ (r & 7)) << 2] =
                    *(const float4*)&Kp[base + (size_t)(k0+r)*DIM + dc*128 + (c4<<2)];
            }
            __syncthreads();
            #pragma unroll 8
            for (int d4 = 0; d4 < 32; ++d4) {
                float4 qa = *(const float4*)&q_s[rq][dc*128 + (d4<<2)];
                float4 ka = *(const float4*)&k_s[kkA][(d4 ^ (kkA & 7)) << 2];
                float4 kb = *(const float4*)&k_s[kkB][(d4 ^ (kkB & 7)) << 2];
                s0 = fmaf(qa.x,ka.x, fmaf(qa.y,ka.y, fmaf(qa.z,ka.z, fmaf(qa.w,ka.w, s0))));
                s1 = fmaf(qa.x,kb.x, fmaf(qa.y,kb.y, fmaf(qa.z,kb.z, fmaf(qa.w,kb.w, s1))));
            }
        }
        {
            int gr = q0 + rq;
            float v0 = s0 * scale, v1 = s1 * scale;
            if (causal) {
                if (k0 + kkA > gr) v0 = -1e30f;
                if (k0 + kkB > gr) v1 = -1e30f;
            }
            s_s[rq][kkA] = v0; s_s[rq][kkB] = v1;
        }
        __syncthreads();
        {   // online softmax update: 32 threads per row, 2 keys each
            int r = tid >> 5, j = tid & 31;
            float a0 = s_s[r][j*2], a1 = s_s[r][j*2+1];
            float tm = fmaxf(a0, a1);
            #pragma unroll
            for (int o = 16; o; o >>= 1) tm = fmaxf(tm, __shfl_xor(tm, o));
            float mold = m_s[r];
            float nm = fmaxf(mold, tm);
            float p0 = __expf(a0 - nm), p1 = __expf(a1 - nm);
            s_s[r][j*2] = p0; s_s[r][j*2+1] = p1;
            float ps = p0 + p1;
            #pragma unroll
            for (int o = 16; o; o >>= 1) ps += __shfl_xor(ps, o);
            if (j == 0) {
                float fr = __expf(mold - nm);
                l_s[r] = l_s[r] * fr + ps;
                m_s[r] = nm;
                f_s[r] = fr;
            }
        }
        __syncthreads();
        #pragma unroll
        for (int r = 0; r < QT; ++r) { float fr = f_s[r]; accv[r][0] *= fr; accv[r][1] *= fr; }
        #pragma unroll 4
        for (int kk4 = 0; kk4 < KT; kk4 += 4) {
            float va[4], vb[4];
            #pragma unroll
            for (int t = 0; t < 4; ++t) {
                const float* vrow = Vp + base + (size_t)(k0 + kk4 + t) * DIM;
                va[t] = vrow[d0]; vb[t] = vrow[d1];
            }
            #pragma unroll
            for (int r = 0; r < QT; ++r) {
                float4 p4 = *(const float4*)&s_s[r][kk4];
                accv[r][0] += p4.x*va[0] + p4.y*va[1] + p4.z*va[2] + p4.w*va[3];
                accv[r][1] += p4.x*vb[0] + p4.y*vb[1] + p4.z*vb[2] + p4.w*vb[3];
            }
        }
        __syncthreads();
    }
    #pragma unroll
    for (int r = 0; r < QT; ++r) {
        float inv = 1.0f / l_s[r];
        size_t o = base + (size_t)(q0 + r) * DIM;
        float v0 = accv[r][0] * inv, v1 = accv[r][1] * inv;
        if (accum) { Op[o + d0] += v0; Op[o + d1] += v1; }
        else       { Op[o + d0]  = v0; Op[o + d1]  = v1; }
    }
}

// ---------------------------------------------------------------- last-row scores (for entropy)
__global__ __launch_bounds__(256) void lastrow_scores(const float* __restrict__ Q,
        const float* __restrict__ K, float* __restrict__ slast)
{
    __shared__ float q_l[DIM];
    int b = blockIdx.y;
    int m = blockIdx.x * 256 + threadIdx.x;
    for (int i = threadIdx.x; i < DIM; i += 256)
        q_l[i] = Q[((size_t)b*SEQ + SEQ-1)*DIM + i];
    __syncthreads();
    const float* kr = K + ((size_t)b*SEQ + m) * DIM;
    float s = 0.f;
    for (int d = 0; d < DIM; d += 4) {
        float4 k4 = *(const float4*)&kr[d];
        s += q_l[d]*k4.x + q_l[d+1]*k4.y + q_l[d+2]*k4.z + q_l[d+3]*k4.w;
    }
    slast[(size_t)b*SEQ + m] = s * RSQRT_D;
}

// ---------------------------------------------------------------- entropy of last-row softmax
__global__ __launch_bounds__(256) void entropy_kernel(const float* __restrict__ slast,
        float* __restrict__ H)
{
    __shared__ float sm[4];
    int b = blockIdx.x, t = threadIdx.x;
    const float* s = slast + (size_t)b * SEQ;
    float v[16];
    float mx = -1e30f;
    #pragma unroll
    for (int j = 0; j < 16; ++j) { v[j] = s[t + j*256]; mx = fmaxf(mx, v[j]); }
    #pragma unroll
    for (int o = 32; o; o >>= 1) mx = fmaxf(mx, __shfl_xor(mx, o));
    __syncthreads();
    if ((t & 63) == 0) sm[t >> 6] = mx;
    __syncthreads();
    mx = fmaxf(fmaxf(sm[0], sm[1]), fmaxf(sm[2], sm[3]));
    float se = 0.f;
    #pragma unroll
    for (int j = 0; j < 16; ++j) { v[j] = expf(v[j] - mx); se += v[j]; }
    se = blk_sum256(se, sm);
    float inv = 1.0f / se;
    float h = 0.f;
    #pragma unroll
    for (int j = 0; j < 16; ++j) {
        float p = fmaxf(v[j] * inv, 1e-9f);
        h -= p * logf(p);
    }
    h = blk_sum256(h, sm);
    if (t == 0) H[b] = h;
}

// ---------------------------------------------------------------- K mean (stage 1, deterministic)
__global__ __launch_bounds__(256) void krep_partial(const float* __restrict__ K,
        float* __restrict__ part)
{
    int b = blockIdx.y, j = blockIdx.x, t = threadIdx.x;
    size_t base = ((size_t)b*SEQ + (size_t)j*256) * DIM;
    float s0 = 0.f, s1 = 0.f;
    for (int r = 0; r < 256; ++r) {
        s0 += K[base + (size_t)r*DIM + t];
        s1 += K[base + (size_t)r*DIM + t + 256];
    }
    size_t o = (size_t)(b*16 + j) * DIM;
    part[o + t] = s0; part[o + t + 256] = s1;
}

// ---------------------------------------------------------------- gate scalar kernel
__global__ __launch_bounds__(256) void scalar_kernel(const float* __restrict__ Qb,
        const float* __restrict__ part, const float* __restrict__ Hent,
        float* __restrict__ gsc)
{
    __shared__ float sm[4];
    __shared__ float sims[BATCH];
    int t = threadIdx.x;
    float qv0 = 0.5f*(Qb[((size_t)0*SEQ + SEQ-1)*DIM + t]     + Qb[((size_t)1*SEQ + SEQ-1)*DIM + t]);
    float qv1 = 0.5f*(Qb[((size_t)0*SEQ + SEQ-1)*DIM + t+256] + Qb[((size_t)1*SEQ + SEQ-1)*DIM + t+256]);
    for (int b = 0; b < BATCH; ++b) {
        float k0 = 0.f, k1 = 0.f;
        for (int j = 0; j < 16; ++j) {
            k0 += part[(size_t)(b*16+j)*DIM + t];
            k1 += part[(size_t)(b*16+j)*DIM + t + 256];
        }
        k0 *= (1.0f/SEQ); k1 *= (1.0f/SEQ);
        float num = blk_sum256(qv0*k0 + qv1*k1, sm);
        float qq  = blk_sum256(qv0*qv0 + qv1*qv1, sm);
        float kk  = blk_sum256(k0*k0 + k1*k1, sm);
        if (t == 0) {
            float na = fmaxf(sqrtf(qq), 1e-8f);
            float nb = fmaxf(sqrtf(kk), 1e-8f);
            sims[b] = num / (na * nb);
        }
        __syncthreads();
    }
    if (t == 0) {
        float H0 = Hent[0], H1 = Hent[1];
        float mn = fminf(H0, H1), mx = fmaxf(H0, H1);
        float den = (mx - mn) + 1e-9f;
        float Hm = 0.5f*((H0 - mn)/den + (H1 - mn)/den);
        float T  = 0.6f + (1.6f - 0.6f) * Hm;
        float th = 0.9f - (0.9f - 0.5f) * Hm;
        float s  = 0.5f * (sims[0] + sims[1]);
        gsc[0] = (s >= th) ? 1.0f : 0.0f;
        gsc[1] = 1.0f / (sqrtf((float)DIM) * T);
    }
}

// ---------------------------------------------------------------- launch
extern "C" void kernel_launch(void* const* d_in, const int* in_sizes, int n_in,
                              void* d_out, int out_size, void* d_ws, size_t ws_size,
                              hipStream_t stream)
{
    (void)in_sizes; (void)n_in; (void)out_size; (void)ws_size;
    const float* x     = (const float*)d_in[0];
    const float* Wq    = (const float*)d_in[1];
    const float* Wk    = (const float*)d_in[2];
    const float* Wv    = (const float*)d_in[3];
    const float* Wp    = (const float*)d_in[4];
    const float* W1    = (const float*)d_in[5];
    const float* b1    = (const float*)d_in[6];
    const float* W2    = (const float*)d_in[7];
    const float* b2    = (const float*)d_in[8];
    const float* gamma = (const float*)d_in[9];
    const float* beta  = (const float*)d_in[10];
    float* out = (float*)d_out;
    float* ws  = (float*)d_ws;
    const size_t NT = (size_t)NROWS * DIM;    // 4,194,304 floats
    float* xn    = ws;              // also reused as h after 2nd LN
    float* Qb    = xn + NT;
    float* Kb    = Qb + NT;
    float* Vb    = Kb + NT;
    float* att   = Vb + NT;         // attention out; later reused as h1 chunk
    float* h1    = att;
    float* slast = att + NT;
    float* Hent  = slast + (size_t)BATCH*SEQ;
    float* kpart = Hent + 8;
    float* gsc   = kpart + (size_t)BATCH*16*DIM;

    ln_kernel<<<NROWS/4, 256, 0, stream>>>(x, gamma, beta, xn);

    dim3 gproj(DIM/128, NROWS/128);
    sgemm_bt<<<gproj, 256, 0, stream>>>(xn, Wq, Qb, nullptr, nullptr, NROWS, DIM, DIM, 0, 0);
    sgemm_bt<<<gproj, 256, 0, stream>>>(xn, Wk, Kb, nullptr, nullptr, NROWS, DIM, DIM, 0, 0);
    sgemm_bt<<<gproj, 256, 0, stream>>>(xn, Wv, Vb, nullptr, nullptr, NROWS, DIM, DIM, 0, 0);

    flash_attn<<<dim3(SEQ/QT, BATCH), 256, 0, stream>>>(Qb, Kb, Vb, att, RSQRT_D,
                                                        nullptr, 1, 0, nullptr);

    lastrow_scores<<<dim3(SEQ/256, BATCH), 256, 0, stream>>>(Qb, Kb, slast);
    entropy_kernel<<<BATCH, 256, 0, stream>>>(slast, Hent);

    // ctx = x + att @ Wp^T   (into d_out)
    sgemm_bt<<<gproj, 256, 0, stream>>>(att, Wp, out, nullptr, x, NROWS, DIM, DIM, 0, 0);

    // h = LN(ctx) into xn
    ln_kernel<<<NROWS/4, 256, 0, stream>>>(out, gamma, beta, xn);

    // FFN, 4 chunks of 2048 rows (h1 reuses att buffer)
    for (int c = 0; c < 4; ++c) {
        const float* hc = xn + (size_t)c * 2048 * DIM;
        float* oc = out + (size_t)c * 2048 * DIM;
        sgemm_bt<<<dim3(FF/128, 2048/128), 256, 0, stream>>>(hc, W1, h1, b1, nullptr,
                                                             2048, FF, DIM, 1, 0);
        sgemm_bt<<<dim3(DIM/128, 2048/128), 256, 0, stream>>>(h1, W2, oc, b2, nullptr,
                                                              2048, DIM, FF, 0, 1);
    }

    krep_partial<<<dim3(16, BATCH), 256, 0, stream>>>(Kb, kpart);
    scalar_kernel<<<1, 256, 0, stream>>>(Qb, kpart, Hent, gsc);

    // gated re-attention: non-causal, temperature-scaled, accumulate into out
    flash_attn<<<dim3(SEQ/QT, BATCH), 256, 0, stream>>>(Qb, Kb, Vb, out, 0.0f,
                                                        gsc + 1, 0, 1, gsc);
}

// Round 2
// 1074.445 us; speedup vs baseline: 3.4521x; 3.4521x over previous
//
#include <hip/hip_runtime.h>
#include <math.h>

#define BATCH 2
#define SEQ 4096
#define DIM 512
#define FF 2048
#define NROWS (BATCH*SEQ)
#define RSQRT_D 0.044194173824159216f  /* 1/sqrt(512) */

typedef __attribute__((ext_vector_type(8))) short short8;
typedef __attribute__((ext_vector_type(4))) float f32x4;

// ---------------------------------------------------------------- helpers
__device__ __forceinline__ float gelu_f(float v) {
    return 0.5f * v * (1.0f + erff(v * 0.70710678118654752440f));
}
__device__ __forceinline__ short bf16b(float x) {
    union { float f; unsigned u; } c; c.f = x;
    unsigned r = (c.u + 0x7FFFu + ((c.u >> 16) & 1u)) >> 16;
    return (short)r;
}
__device__ __forceinline__ float bf16f(short h) {
    union { unsigned u; float f; } c; c.u = ((unsigned)(unsigned short)h) << 16;
    return c.f;
}
__device__ __forceinline__ void gload16(const void* g, void* l) {
    __builtin_amdgcn_global_load_lds(
        (const __attribute__((address_space(1))) unsigned int*)g,
        (__attribute__((address_space(3))) unsigned int*)l, 16, 0, 0);
}
__device__ __forceinline__ float blk_sum256(float v, volatile float* sm) {
    #pragma unroll
    for (int o = 32; o; o >>= 1) v += __shfl_xor(v, o);
    __syncthreads();
    if ((threadIdx.x & 63) == 0) sm[threadIdx.x >> 6] = v;
    __syncthreads();
    return sm[0] + sm[1] + sm[2] + sm[3];
}

// ---------------------------------------------------------------- f32 -> bf16 convert
__global__ __launch_bounds__(256) void f2bf(const float* __restrict__ in,
                                            short* __restrict__ out, int n8)
{
    int i = blockIdx.x * 256 + threadIdx.x;
    if (i >= n8) return;
    const float4* p = (const float4*)(in + (size_t)i * 8);
    float4 a = p[0], b = p[1];
    short8 r;
    r[0]=bf16b(a.x); r[1]=bf16b(a.y); r[2]=bf16b(a.z); r[3]=bf16b(a.w);
    r[4]=bf16b(b.x); r[5]=bf16b(b.y); r[6]=bf16b(b.z); r[7]=bf16b(b.w);
    *(short8*)(out + (size_t)i * 8) = r;
}

// ---------------------------------------------------------------- layernorm (f32 in, bf16 out)
__global__ __launch_bounds__(256) void ln_kernel(const float* __restrict__ x,
        const float* __restrict__ g, const float* __restrict__ be,
        short* __restrict__ o)
{
    int row  = blockIdx.x * 4 + (threadIdx.x >> 6);
    int lane = threadIdx.x & 63;
    const float4* xr = (const float4*)(x + (size_t)row * DIM);
    float4 v0 = xr[lane*2], v1 = xr[lane*2+1];
    float s = v0.x+v0.y+v0.z+v0.w + v1.x+v1.y+v1.z+v1.w;
    #pragma unroll
    for (int off = 32; off; off >>= 1) s += __shfl_xor(s, off);
    float mu = s * (1.0f/DIM);
    float d[8] = {v0.x-mu, v0.y-mu, v0.z-mu, v0.w-mu, v1.x-mu, v1.y-mu, v1.z-mu, v1.w-mu};
    float q = 0.f;
    #pragma unroll
    for (int j = 0; j < 8; ++j) q += d[j]*d[j];
    #pragma unroll
    for (int off = 32; off; off >>= 1) q += __shfl_xor(q, off);
    float rs = rsqrtf(q * (1.0f/DIM) + 1e-5f);
    const float4* g4 = (const float4*)g;
    const float4* b4 = (const float4*)be;
    float4 ga = g4[lane*2], gb = g4[lane*2+1];
    float4 ba = b4[lane*2], bb = b4[lane*2+1];
    float gv[8] = {ga.x,ga.y,ga.z,ga.w, gb.x,gb.y,gb.z,gb.w};
    float bv[8] = {ba.x,ba.y,ba.z,ba.w, bb.x,bb.y,bb.z,bb.w};
    short8 r;
    #pragma unroll
    for (int j = 0; j < 8; ++j) r[j] = bf16b(d[j]*rs*gv[j] + bv[j]);
    *(short8*)(o + (size_t)row * DIM + lane*8) = r;
}

// ---------------------------------------------------------------- bf16 MFMA GEMM
// C[M,N] = A[M,K] * W[N,K]^T (+bias)(gelu)(+res); Cf fp32 (opt, accum opt), Cb bf16 (opt)
// 128x128 tile, BK=32, 256 threads (4 waves, 2x2 of 64x64), global_load_lds staging
__global__ __launch_bounds__(256) void gemm_bf16(
        const short* __restrict__ A, const short* __restrict__ W,
        const float* __restrict__ bias, const float* __restrict__ res,
        float* __restrict__ Cf, short* __restrict__ Cb,
        int M, int N, int K, int act, int accum)
{
    __shared__ short As[128*32];
    __shared__ short Ws[128*32];
    int tid = threadIdx.x;
    int m0 = blockIdx.y * 128, n0 = blockIdx.x * 128;
    int w = tid >> 6, lane = tid & 63;
    int wr = (w >> 1) * 64, wc = (w & 1) * 64;
    int lr = lane & 15, lg = lane >> 4;
    int srow = tid >> 2, skoff = (tid & 3) * 8;   // staging: 16B per thread per chunk
    f32x4 acc[4][4];
    f32x4 zero = {0.f, 0.f, 0.f, 0.f};
    #pragma unroll
    for (int i = 0; i < 4; ++i)
        #pragma unroll
        for (int j = 0; j < 4; ++j) acc[i][j] = zero;

    for (int k0 = 0; k0 < K; k0 += 32) {
        __syncthreads();
        gload16(A + (size_t)(m0 + srow) * K + k0 + skoff,      As + tid*8);
        gload16(A + (size_t)(m0 + 64 + srow) * K + k0 + skoff, As + 2048 + tid*8);
        gload16(W + (size_t)(n0 + srow) * K + k0 + skoff,      Ws + tid*8);
        gload16(W + (size_t)(n0 + 64 + srow) * K + k0 + skoff, Ws + 2048 + tid*8);
        __syncthreads();
        short8 a[4], b[4];
        #pragma unroll
        for (int i = 0; i < 4; ++i) a[i] = *(const short8*)(As + (wr + i*16 + lr)*32 + lg*8);
        #pragma unroll
        for (int j = 0; j < 4; ++j) b[j] = *(const short8*)(Ws + (wc + j*16 + lr)*32 + lg*8);
        #pragma unroll
        for (int i = 0; i < 4; ++i)
            #pragma unroll
            for (int j = 0; j < 4; ++j)
                acc[i][j] = __builtin_amdgcn_mfma_f32_16x16x32_bf16(a[i], b[j], acc[i][j], 0, 0, 0);
    }

    #pragma unroll
    for (int i = 0; i < 4; ++i) {
        #pragma unroll
        for (int r = 0; r < 4; ++r) {
            size_t m = (size_t)m0 + wr + i*16 + lg*4 + r;
            #pragma unroll
            for (int j = 0; j < 4; ++j) {
                int n = n0 + wc + j*16 + lr;
                float v = acc[i][j][r];
                if (bias) v += bias[n];
                if (act)  v = gelu_f(v);
                if (res)  v += res[m * N + n];
                size_t idx = m * N + n;
                if (Cf) { if (accum) Cf[idx] += v; else Cf[idx] = v; }
                if (Cb) Cb[idx] = bf16b(v);
            }
        }
    }
}

// ---------------------------------------------------------------- bf16 tile transpose V[b][l][d] -> Vt[b][d][l]
__global__ __launch_bounds__(256) void vtrans(const short* __restrict__ V,
                                              short* __restrict__ Vt)
{
    __shared__ short t_s[64][72];
    int l0 = blockIdx.x * 64, d0 = blockIdx.y * 64, b = blockIdx.z;
    int t = threadIdx.x;
    const short* src = V + (size_t)b * SEQ * DIM;
    #pragma unroll
    for (int it = 0; it < 2; ++it) {
        int r = (t >> 3) + it * 32, c = (t & 7) * 8;
        *(short8*)&t_s[r][c] = *(const short8*)(src + (size_t)(l0 + r) * DIM + d0 + c);
    }
    __syncthreads();
    short* dst = Vt + (size_t)b * DIM * SEQ;
    #pragma unroll
    for (int it = 0; it < 2; ++it) {
        int r = (t >> 3) + it * 32, c = (t & 7) * 8;
        short8 v;
        #pragma unroll
        for (int j = 0; j < 8; ++j) v[j] = t_s[c + j][r];
        *(short8*)(dst + (size_t)(d0 + r) * SEQ + l0 + c) = v;
    }
}

// ---------------------------------------------------------------- MFMA flash attention
// QBLK=32 q-rows/block, 8 waves: wave w -> rw=w&1 (16-row group), kp=w>>1 (K-partition of 4).
// KTILE=64 keys/tile; direct-global K and Vt fragment loads; P via swizzled wave-private LDS.
#define QBLK 32
__global__ __launch_bounds__(512, 2) void attn_mfma(
        const short* __restrict__ Q, const short* __restrict__ K,
        const short* __restrict__ Vt, short* __restrict__ Ob,
        float* __restrict__ Of, float scale, const float* __restrict__ scale_ptr,
        const float* __restrict__ gate, int causal)
{
    if (gate && gate[0] == 0.0f) return;
    if (scale_ptr) scale = scale_ptr[0];
    __shared__ short p_s[8 * 1024];          // per-wave 16x64 bf16 P, XOR-swizzled
    __shared__ float obuf[2][16][128];
    __shared__ float ml_s[8][2][16];
    __shared__ float inv_s[2][16];
    int tid = threadIdx.x;
    int w = tid >> 6, lane = tid & 63;
    int rw = w & 1, kp = w >> 1;
    int lr = lane & 15, lg = lane >> 4;
    int b = blockIdx.y;
    int q0 = blockIdx.x * QBLK;
    int qw0 = q0 + rw * 16;
    size_t kbase = (size_t)b * SEQ * DIM;
    size_t vbase = (size_t)b * DIM * SEQ;
    int T = causal ? ((q0 + QBLK - 1) / 64 + 1) : (SEQ / 64);

    short8 qf[16];
    #pragma unroll
    for (int kc = 0; kc < 16; ++kc)
        qf[kc] = *(const short8*)(Q + kbase + (size_t)(qw0 + lr) * DIM + kc*32 + lg*8);

    f32x4 zero = {0.f, 0.f, 0.f, 0.f};
    f32x4 o[32];
    #pragma unroll
    for (int df = 0; df < 32; ++df) o[df] = zero;
    float mreg[4] = {-1e30f, -1e30f, -1e30f, -1e30f};
    float lreg[4] = {0.f, 0.f, 0.f, 0.f};

    for (int t = kp; t < T; t += 4) {
        int k0 = t * 64;
        f32x4 ss[4];
        #pragma unroll
        for (int kf = 0; kf < 4; ++kf) {
            f32x4 acc = zero;
            const short* kr = K + kbase + (size_t)(k0 + kf*16 + lr) * DIM + lg*8;
            #pragma unroll
            for (int kc = 0; kc < 16; ++kc) {
                short8 kf8 = *(const short8*)(kr + kc*32);
                acc = __builtin_amdgcn_mfma_f32_16x16x32_bf16(qf[kc], kf8, acc, 0, 0, 0);
            }
            #pragma unroll
            for (int r = 0; r < 4; ++r) acc[r] *= scale;
            if (causal && (k0 + 63 > q0)) {
                int col = k0 + kf*16 + lr;
                #pragma unroll
                for (int r = 0; r < 4; ++r)
                    if (col > qw0 + lg*4 + r) acc[r] = -1e30f;
            }
            ss[kf] = acc;
        }
        // ---- online softmax (rows owned by 16-lane groups)
        float mt[4], fr[4], ps[4];
        #pragma unroll
        for (int r = 0; r < 4; ++r) {
            float v = fmaxf(fmaxf(ss[0][r], ss[1][r]), fmaxf(ss[2][r], ss[3][r]));
            v = fmaxf(v, __shfl_xor(v, 1));
            v = fmaxf(v, __shfl_xor(v, 2));
            v = fmaxf(v, __shfl_xor(v, 4));
            v = fmaxf(v, __shfl_xor(v, 8));
            float mn = fmaxf(mreg[r], v);
            fr[r] = __expf(mreg[r] - mn);
            mreg[r] = mn;
            mt[r] = mn;
        }
        #pragma unroll
        for (int kf = 0; kf < 4; ++kf)
            #pragma unroll
            for (int r = 0; r < 4; ++r)
                ss[kf][r] = __expf(ss[kf][r] - mt[r]);
        #pragma unroll
        for (int r = 0; r < 4; ++r) {
            float v = ss[0][r] + ss[1][r] + ss[2][r] + ss[3][r];
            v += __shfl_xor(v, 1);
            v += __shfl_xor(v, 2);
            v += __shfl_xor(v, 4);
            v += __shfl_xor(v, 8);
            ps[r] = v;
            lreg[r] = lreg[r] * fr[r] + ps[r];
        }
        #pragma unroll
        for (int df = 0; df < 32; ++df) {
            #pragma unroll
            for (int r = 0; r < 4; ++r) o[df][r] *= fr[r];
        }
        // ---- P -> LDS (bf16, XOR-swizzled 16B blocks)
        #pragma unroll
        for (int kf = 0; kf < 4; ++kf) {
            int blk = kf*2 + (lr >> 3);
            #pragma unroll
            for (int r = 0; r < 4; ++r) {
                int row = lg*4 + r;
                p_s[w*1024 + row*64 + ((blk ^ (row & 7)) << 3) + (lr & 7)] = bf16b(ss[kf][r]);
            }
        }
        // ---- PV
        #pragma unroll
        for (int ks = 0; ks < 2; ++ks) {
            short8 pa = *(const short8*)&p_s[w*1024 + lr*64 + (((ks*4 + lg) ^ (lr & 7)) << 3)];
            const short* vr = Vt + vbase + (size_t)lr * SEQ + k0 + ks*32 + lg*8;
            #pragma unroll
            for (int df = 0; df < 32; ++df) {
                short8 vf = *(const short8*)(vr + (size_t)df * 16 * SEQ);
                o[df] = __builtin_amdgcn_mfma_f32_16x16x32_bf16(pa, vf, o[df], 0, 0, 0);
            }
        }
    }

    // ---- merge 4 K-partitions per row-group
    if (lr == 0) {
        #pragma unroll
        for (int r = 0; r < 4; ++r) {
            ml_s[w][0][lg*4 + r] = mreg[r];
            ml_s[w][1][lg*4 + r] = lreg[r];
        }
    }
    __syncthreads();
    float f[4], inv[4];
    #pragma unroll
    for (int r = 0; r < 4; ++r) {
        int row = lg*4 + r;
        float M = -1e30f;
        #pragma unroll
        for (int k2 = 0; k2 < 4; ++k2) M = fmaxf(M, ml_s[2*k2 + rw][0][row]);
        float L = 0.f;
        #pragma unroll
        for (int k2 = 0; k2 < 4; ++k2)
            L += ml_s[2*k2 + rw][1][row] * __expf(ml_s[2*k2 + rw][0][row] - M);
        f[r] = __expf(mreg[r] - M);
        inv[r] = 1.0f / L;
    }
    if (kp == 0 && lr == 0) {
        #pragma unroll
        for (int r = 0; r < 4; ++r) inv_s[rw][lg*4 + r] = inv[r];
    }
    #pragma unroll
    for (int dc = 0; dc < 4; ++dc) {
        #pragma unroll
        for (int ph = 0; ph < 4; ++ph) {
            if (kp == ph) {
                #pragma unroll
                for (int d2 = 0; d2 < 8; ++d2) {
                    #pragma unroll
                    for (int r = 0; r < 4; ++r) {
                        float v = o[dc*8 + d2][r] * f[r];
                        if (ph == 0) obuf[rw][lg*4 + r][d2*16 + lr] = v;
                        else         obuf[rw][lg*4 + r][d2*16 + lr] += v;
                    }
                }
            }
            __syncthreads();
        }
        {
            int rwo = tid >> 8, rr = (tid >> 4) & 15, c0 = (tid & 15) * 8;
            float iv = inv_s[rwo][rr];
            size_t gbase = (size_t)b * SEQ * DIM + (size_t)(q0 + rwo*16 + rr) * DIM + dc*128 + c0;
            if (Ob) {
                short8 pk;
                #pragma unroll
                for (int j = 0; j < 8; ++j) pk[j] = bf16b(obuf[rwo][rr][c0 + j] * iv);
                *(short8*)(Ob + gbase) = pk;
            } else {
                #pragma unroll
                for (int j = 0; j < 8; ++j) Of[gbase + j] += obuf[rwo][rr][c0 + j] * iv;
            }
        }
        __syncthreads();
    }
}

// ---------------------------------------------------------------- last-row scores (bf16 in)
__global__ __launch_bounds__(256) void lastrow_scores(const short* __restrict__ Q,
        const short* __restrict__ K, float* __restrict__ slast)
{
    __shared__ float q_l[DIM];
    int b = blockIdx.y;
    int m = blockIdx.x * 256 + threadIdx.x;
    for (int i = threadIdx.x; i < DIM; i += 256)
        q_l[i] = bf16f(Q[((size_t)b*SEQ + SEQ-1)*DIM + i]);
    __syncthreads();
    const short* kr = K + ((size_t)b*SEQ + m) * DIM;
    float s = 0.f;
    for (int d = 0; d < DIM; d += 8) {
        short8 k8 = *(const short8*)(kr + d);
        #pragma unroll
        for (int j = 0; j < 8; ++j) s += q_l[d + j] * bf16f(k8[j]);
    }
    slast[(size_t)b*SEQ + m] = s * RSQRT_D;
}

// ---------------------------------------------------------------- entropy of last-row softmax
__global__ __launch_bounds__(256) void entropy_kernel(const float* __restrict__ slast,
        float* __restrict__ H)
{
    __shared__ float sm[4];
    int b = blockIdx.x, t = threadIdx.x;
    const float* s = slast + (size_t)b * SEQ;
    float v[16];
    float mx = -1e30f;
    #pragma unroll
    for (int j = 0; j < 16; ++j) { v[j] = s[t + j*256]; mx = fmaxf(mx, v[j]); }
    #pragma unroll
    for (int o = 32; o; o >>= 1) mx = fmaxf(mx, __shfl_xor(mx, o));
    __syncthreads();
    if ((t & 63) == 0) sm[t >> 6] = mx;
    __syncthreads();
    mx = fmaxf(fmaxf(sm[0], sm[1]), fmaxf(sm[2], sm[3]));
    float se = 0.f;
    #pragma unroll
    for (int j = 0; j < 16; ++j) { v[j] = expf(v[j] - mx); se += v[j]; }
    se = blk_sum256(se, sm);
    float inv = 1.0f / se;
    float h = 0.f;
    #pragma unroll
    for (int j = 0; j < 16; ++j) {
        float p = fmaxf(v[j] * inv, 1e-9f);
        h -= p * logf(p);
    }
    h = blk_sum256(h, sm);
    if (t == 0) H[b] = h;
}

// ---------------------------------------------------------------- K mean partials (bf16 in)
__global__ __launch_bounds__(256) void krep_partial(const short* __restrict__ K,
        float* __restrict__ part)
{
    int b = blockIdx.y, j = blockIdx.x, t = threadIdx.x;
    size_t base = ((size_t)b*SEQ + (size_t)j*256) * DIM;
    float s0 = 0.f, s1 = 0.f;
    for (int r = 0; r < 256; ++r) {
        s0 += bf16f(K[base + (size_t)r*DIM + t]);
        s1 += bf16f(K[base + (size_t)r*DIM + t + 256]);
    }
    size_t o = (size_t)(b*16 + j) * DIM;
    part[o + t] = s0; part[o + t + 256] = s1;
}

// ---------------------------------------------------------------- gate scalar kernel
__global__ __launch_bounds__(256) void scalar_kernel(const short* __restrict__ Qb,
        const float* __restrict__ part, const float* __restrict__ Hent,
        float* __restrict__ gsc)
{
    __shared__ float sm[4];
    __shared__ float sims[BATCH];
    int t = threadIdx.x;
    float qv0 = 0.5f*(bf16f(Qb[((size_t)0*SEQ + SEQ-1)*DIM + t])     + bf16f(Qb[((size_t)1*SEQ + SEQ-1)*DIM + t]));
    float qv1 = 0.5f*(bf16f(Qb[((size_t)0*SEQ + SEQ-1)*DIM + t+256]) + bf16f(Qb[((size_t)1*SEQ + SEQ-1)*DIM + t+256]));
    for (int b = 0; b < BATCH; ++b) {
        float k0 = 0.f, k1 = 0.f;
        for (int j = 0; j < 16; ++j) {
            k0 += part[(size_t)(b*16+j)*DIM + t];
            k1 += part[(size_t)(b*16+j)*DIM + t + 256];
        }
        k0 *= (1.0f/SEQ); k1 *= (1.0f/SEQ);
        float num = blk_sum256(qv0*k0 + qv1*k1, sm);
        float qq  = blk_sum256(qv0*qv0 + qv1*qv1, sm);
        float kk  = blk_sum256(k0*k0 + k1*k1, sm);
        if (t == 0) {
            float na = fmaxf(sqrtf(qq), 1e-8f);
            float nb = fmaxf(sqrtf(kk), 1e-8f);
            sims[b] = num / (na * nb);
        }
        __syncthreads();
    }
    if (t == 0) {
        float H0 = Hent[0], H1 = Hent[1];
        float mn = fminf(H0, H1), mx = fmaxf(H0, H1);
        float den = (mx - mn) + 1e-9f;
        float Hm = 0.5f*((H0 - mn)/den + (H1 - mn)/den);
        float T  = 0.6f + (1.6f - 0.6f) * Hm;
        float th = 0.9f - (0.9f - 0.5f) * Hm;
        float s  = 0.5f * (sims[0] + sims[1]);
        gsc[0] = (s >= th) ? 1.0f : 0.0f;
        gsc[1] = 1.0f / (sqrtf((float)DIM) * T);
    }
}

// ---------------------------------------------------------------- launch
extern "C" void kernel_launch(void* const* d_in, const int* in_sizes, int n_in,
                              void* d_out, int out_size, void* d_ws, size_t ws_size,
                              hipStream_t stream)
{
    (void)in_sizes; (void)n_in; (void)out_size; (void)ws_size;
    const float* x     = (const float*)d_in[0];
    const float* Wq    = (const float*)d_in[1];
    const float* Wk    = (const float*)d_in[2];
    const float* Wv    = (const float*)d_in[3];
    const float* Wp    = (const float*)d_in[4];
    const float* W1    = (const float*)d_in[5];
    const float* b1    = (const float*)d_in[6];
    const float* W2    = (const float*)d_in[7];
    const float* b2    = (const float*)d_in[8];
    const float* gamma = (const float*)d_in[9];
    const float* beta  = (const float*)d_in[10];
    float* out = (float*)d_out;

    const size_t NT = (size_t)NROWS * DIM;   // 4,194,304
    short* bws   = (short*)d_ws;
    short* xn_bf = bws;                      // 4M elems (also h after LN2)
    short* Qbf   = xn_bf + NT;
    short* Kbf   = Qbf + NT;
    short* Vt    = Kbf + NT;
    short* att   = Vt + NT;
    short* h1    = att + NT;                 // 8M elems (V tmp, then FFN hidden chunks)
    short* Wqb   = h1 + (size_t)8388608;
    short* Wkb   = Wqb + 262144;
    short* Wvb   = Wkb + 262144;
    short* Wpb   = Wvb + 262144;
    short* W1b   = Wpb + 262144;
    short* W2b   = W1b + 1048576;
    float* slast = (float*)(W2b + 1048576);
    float* Hent  = slast + 8192;
    float* kpart = Hent + 8;
    float* gsc   = kpart + 16384;

    // weights -> bf16
    f2bf<<<128, 256, 0, stream>>>(Wq, Wqb, 32768);
    f2bf<<<128, 256, 0, stream>>>(Wk, Wkb, 32768);
    f2bf<<<128, 256, 0, stream>>>(Wv, Wvb, 32768);
    f2bf<<<128, 256, 0, stream>>>(Wp, Wpb, 32768);
    f2bf<<<512, 256, 0, stream>>>(W1, W1b, 131072);
    f2bf<<<512, 256, 0, stream>>>(W2, W2b, 131072);

    ln_kernel<<<NROWS/4, 256, 0, stream>>>(x, gamma, beta, xn_bf);

    dim3 gproj(DIM/128, NROWS/128);
    gemm_bf16<<<gproj, 256, 0, stream>>>(xn_bf, Wqb, nullptr, nullptr, nullptr, Qbf, NROWS, DIM, DIM, 0, 0);
    gemm_bf16<<<gproj, 256, 0, stream>>>(xn_bf, Wkb, nullptr, nullptr, nullptr, Kbf, NROWS, DIM, DIM, 0, 0);
    gemm_bf16<<<gproj, 256, 0, stream>>>(xn_bf, Wvb, nullptr, nullptr, nullptr, h1,  NROWS, DIM, DIM, 0, 0);
    vtrans<<<dim3(SEQ/64, DIM/64, BATCH), 256, 0, stream>>>(h1, Vt);

    attn_mfma<<<dim3(SEQ/QBLK, BATCH), 512, 0, stream>>>(Qbf, Kbf, Vt, att, nullptr,
                                                         RSQRT_D, nullptr, nullptr, 1);

    lastrow_scores<<<dim3(SEQ/256, BATCH), 256, 0, stream>>>(Qbf, Kbf, slast);
    entropy_kernel<<<BATCH, 256, 0, stream>>>(slast, Hent);

    // ctx = x + att @ Wp^T   (fp32 into d_out)
    gemm_bf16<<<gproj, 256, 0, stream>>>(att, Wpb, nullptr, x, out, nullptr, NROWS, DIM, DIM, 0, 0);

    // h = LN(ctx) -> xn_bf
    ln_kernel<<<NROWS/4, 256, 0, stream>>>(out, gamma, beta, xn_bf);

    // FFN: 2 chunks of 4096 rows
    for (int c = 0; c < 2; ++c) {
        const short* hc = xn_bf + (size_t)c * 4096 * DIM;
        float* oc = out + (size_t)c * 4096 * DIM;
        gemm_bf16<<<dim3(FF/128, 4096/128), 256, 0, stream>>>(hc, W1b, b1, nullptr, nullptr, h1,
                                                              4096, FF, DIM, 1, 0);
        gemm_bf16<<<dim3(DIM/128, 4096/128), 256, 0, stream>>>(h1, W2b, b2, nullptr, oc, nullptr,
                                                               4096, DIM, FF, 0, 1);
    }

    krep_partial<<<dim3(16, BATCH), 256, 0, stream>>>(Kbf, kpart);
    scalar_kernel<<<1, 256, 0, stream>>>(Qbf, kpart, Hent, gsc);

    // gated re-attention (non-causal, temperature), accumulate fp32 into out
    attn_mfma<<<dim3(SEQ/QBLK, BATCH), 512, 0, stream>>>(Qbf, Kbf, Vt, nullptr, out,
                                                         0.0f, gsc + 1, gsc, 0);
}

// Round 3
// 734.685 us; speedup vs baseline: 5.0486x; 1.4625x over previous
//
#include <hip/hip_runtime.h>
#include <math.h>

#define BATCH 2
#define SEQ 4096
#define DIM 512
#define FF 2048
#define NROWS (BATCH*SEQ)
#define CHUNK 1024
#define RSQRT_D 0.044194173824159216f  /* 1/sqrt(512) */

typedef __attribute__((ext_vector_type(8))) short short8;
typedef __attribute__((ext_vector_type(4))) short short4v;
typedef __attribute__((ext_vector_type(4))) float f32x4;

// ---------------------------------------------------------------- helpers
__device__ __forceinline__ float gelu_f(float v) {
    return 0.5f * v * (1.0f + erff(v * 0.70710678118654752440f));
}
__device__ __forceinline__ short bf16b(float x) {
    union { float f; unsigned u; } c; c.f = x;
    unsigned r = (c.u + 0x7FFFu + ((c.u >> 16) & 1u)) >> 16;
    return (short)r;
}
__device__ __forceinline__ float bf16f(short h) {
    union { unsigned u; float f; } c; c.u = ((unsigned)(unsigned short)h) << 16;
    return c.f;
}
__device__ __forceinline__ void gload16(const void* g, void* l) {
    __builtin_amdgcn_global_load_lds(
        (const __attribute__((address_space(1))) unsigned int*)g,
        (__attribute__((address_space(3))) unsigned int*)l, 16, 0, 0);
}
__device__ __forceinline__ float blk_sum256(float v, volatile float* sm) {
    #pragma unroll
    for (int o = 32; o; o >>= 1) v += __shfl_xor(v, o);
    __syncthreads();
    if ((threadIdx.x & 63) == 0) sm[threadIdx.x >> 6] = v;
    __syncthreads();
    return sm[0] + sm[1] + sm[2] + sm[3];
}

// ---------------------------------------------------------------- f32 -> bf16 convert
__global__ __launch_bounds__(256) void f2bf(const float* __restrict__ in,
                                            short* __restrict__ out, int n8)
{
    int i = blockIdx.x * 256 + threadIdx.x;
    if (i >= n8) return;
    const float4* p = (const float4*)(in + (size_t)i * 8);
    float4 a = p[0], b = p[1];
    short8 r;
    r[0]=bf16b(a.x); r[1]=bf16b(a.y); r[2]=bf16b(a.z); r[3]=bf16b(a.w);
    r[4]=bf16b(b.x); r[5]=bf16b(b.y); r[6]=bf16b(b.z); r[7]=bf16b(b.w);
    *(short8*)(out + (size_t)i * 8) = r;
}

// ---------------------------------------------------------------- layernorm (f32 in, bf16 out)
__global__ __launch_bounds__(256) void ln_kernel(const float* __restrict__ x,
        const float* __restrict__ g, const float* __restrict__ be,
        short* __restrict__ o)
{
    int row  = blockIdx.x * 4 + (threadIdx.x >> 6);
    int lane = threadIdx.x & 63;
    const float4* xr = (const float4*)(x + (size_t)row * DIM);
    float4 v0 = xr[lane*2], v1 = xr[lane*2+1];
    float s = v0.x+v0.y+v0.z+v0.w + v1.x+v1.y+v1.z+v1.w;
    #pragma unroll
    for (int off = 32; off; off >>= 1) s += __shfl_xor(s, off);
    float mu = s * (1.0f/DIM);
    float d[8] = {v0.x-mu, v0.y-mu, v0.z-mu, v0.w-mu, v1.x-mu, v1.y-mu, v1.z-mu, v1.w-mu};
    float q = 0.f;
    #pragma unroll
    for (int j = 0; j < 8; ++j) q += d[j]*d[j];
    #pragma unroll
    for (int off = 32; off; off >>= 1) q += __shfl_xor(q, off);
    float rs = rsqrtf(q * (1.0f/DIM) + 1e-5f);
    const float4* g4 = (const float4*)g;
    const float4* b4 = (const float4*)be;
    float4 ga = g4[lane*2], gb = g4[lane*2+1];
    float4 ba = b4[lane*2], bb = b4[lane*2+1];
    float gv[8] = {ga.x,ga.y,ga.z,ga.w, gb.x,gb.y,gb.z,gb.w};
    float bv[8] = {ba.x,ba.y,ba.z,ba.w, bb.x,bb.y,bb.z,bb.w};
    short8 r;
    #pragma unroll
    for (int j = 0; j < 8; ++j) r[j] = bf16b(d[j]*rs*gv[j] + bv[j]);
    *(short8*)(o + (size_t)row * DIM + lane*8) = r;
}

// ---------------------------------------------------------------- bf16 MFMA GEMM (unchanged from r2)
__global__ __launch_bounds__(256) void gemm_bf16(
        const short* __restrict__ A, const short* __restrict__ W,
        const float* __restrict__ bias, const float* __restrict__ res,
        float* __restrict__ Cf, short* __restrict__ Cb,
        int M, int N, int K, int act, int accum)
{
    __shared__ short As[128*32];
    __shared__ short Ws[128*32];
    int tid = threadIdx.x;
    int m0 = blockIdx.y * 128, n0 = blockIdx.x * 128;
    int w = tid >> 6, lane = tid & 63;
    int wr = (w >> 1) * 64, wc = (w & 1) * 64;
    int lr = lane & 15, lg = lane >> 4;
    int srow = tid >> 2, skoff = (tid & 3) * 8;
    f32x4 acc[4][4];
    f32x4 zero = {0.f, 0.f, 0.f, 0.f};
    #pragma unroll
    for (int i = 0; i < 4; ++i)
        #pragma unroll
        for (int j = 0; j < 4; ++j) acc[i][j] = zero;

    for (int k0 = 0; k0 < K; k0 += 32) {
        __syncthreads();
        gload16(A + (size_t)(m0 + srow) * K + k0 + skoff,      As + tid*8);
        gload16(A + (size_t)(m0 + 64 + srow) * K + k0 + skoff, As + 2048 + tid*8);
        gload16(W + (size_t)(n0 + srow) * K + k0 + skoff,      Ws + tid*8);
        gload16(W + (size_t)(n0 + 64 + srow) * K + k0 + skoff, Ws + 2048 + tid*8);
        __syncthreads();
        short8 a[4], b[4];
        #pragma unroll
        for (int i = 0; i < 4; ++i) a[i] = *(const short8*)(As + (wr + i*16 + lr)*32 + lg*8);
        #pragma unroll
        for (int j = 0; j < 4; ++j) b[j] = *(const short8*)(Ws + (wc + j*16 + lr)*32 + lg*8);
        #pragma unroll
        for (int i = 0; i < 4; ++i)
            #pragma unroll
            for (int j = 0; j < 4; ++j)
                acc[i][j] = __builtin_amdgcn_mfma_f32_16x16x32_bf16(a[i], b[j], acc[i][j], 0, 0, 0);
    }

    #pragma unroll
    for (int i = 0; i < 4; ++i) {
        #pragma unroll
        for (int r = 0; r < 4; ++r) {
            size_t m = (size_t)m0 + wr + i*16 + lg*4 + r;
            #pragma unroll
            for (int j = 0; j < 4; ++j) {
                int n = n0 + wc + j*16 + lr;
                float v = acc[i][j][r];
                if (bias) v += bias[n];
                if (act)  v = gelu_f(v);
                if (res)  v += res[m * N + n];
                size_t idx = m * N + n;
                if (Cf) { if (accum) Cf[idx] += v; else Cf[idx] = v; }
                if (Cb) Cb[idx] = bf16b(v);
            }
        }
    }
}

// ---------------------------------------------------------------- bf16 tile transpose V[b][l][d] -> Vt[b][d][l]
__global__ __launch_bounds__(256) void vtrans(const short* __restrict__ V,
                                              short* __restrict__ Vt)
{
    __shared__ short t_s[64][72];
    int l0 = blockIdx.x * 64, d0 = blockIdx.y * 64, b = blockIdx.z;
    int t = threadIdx.x;
    const short* src = V + (size_t)b * SEQ * DIM;
    #pragma unroll
    for (int it = 0; it < 2; ++it) {
        int r = (t >> 3) + it * 32, c = (t & 7) * 8;
        *(short8*)&t_s[r][c] = *(const short8*)(src + (size_t)(l0 + r) * DIM + d0 + c);
    }
    __syncthreads();
    short* dst = Vt + (size_t)b * DIM * SEQ;
    #pragma unroll
    for (int it = 0; it < 2; ++it) {
        int r = (t >> 3) + it * 32, c = (t & 7) * 8;
        short8 v;
        #pragma unroll
        for (int j = 0; j < 8; ++j) v[j] = t_s[c + j][r];
        *(short8*)(dst + (size_t)(d0 + r) * SEQ + l0 + c) = v;
    }
}

// ---------------------------------------------------------------- chunked flash attention, partials
// 256 thr, 4 waves: qw = w&1 (32-row q-subtile), dh = w>>1 (256-dim half).
// Block = (q-tile of 64 rows, K-chunk of 1024). KT=32 keys/tile.
// Vt tile staged in LDS (swizzled via pre-swizzled global source); K direct from L2.
// Partial scores exchanged via LDS (dh0 -> dh1), dh1 does softmax, shares P + fr.
__global__ __launch_bounds__(256, 2) void attn_part(
        const short* __restrict__ Q, const short* __restrict__ K,
        const short* __restrict__ Vt, short* __restrict__ Opart,
        float* __restrict__ Mpart, float* __restrict__ Lpart,
        float scale, const float* __restrict__ scale_ptr,
        const float* __restrict__ gate, int causal)
{
    if (gate && gate[0] == 0.0f) return;
    if (scale_ptr) scale = scale_ptr[0];
    __shared__ short vt_s[512 * 32];           // [d][osw 4][8 keys], 32 KB
    __shared__ float part_s[2][2][2][256];     // [qw][qi][kf][lane*4], 8 KB
    __shared__ short p_s[2][2][512];           // [qw][qi][row*32 + swz], 2 KB bf16
    __shared__ float f_s[64];
    int tid = threadIdx.x, w = tid >> 6, lane = tid & 63;
    int qw = w & 1, dh = w >> 1;
    int lr = lane & 15, lg = lane >> 4;
    int j = blockIdx.x, c = blockIdx.y, b = blockIdx.z;
    int q0 = j * 64, cstart = c * CHUNK;
    if (causal && cstart > q0 + 63) return;
    int kend = causal ? min(cstart + CHUNK, q0 + 64) : (cstart + CHUNK);
    int T = (kend - cstart) >> 5;
    size_t bofs = (size_t)b * SEQ * DIM;
    size_t vofs = (size_t)b * DIM * SEQ;

    // Q fragments: rows q0+qw*32+qi*16+lr, dims dh*256 + kc*32 + lg*8
    short8 qf[2][8];
    #pragma unroll
    for (int qi = 0; qi < 2; ++qi)
        #pragma unroll
        for (int kc = 0; kc < 8; ++kc)
            qf[qi][kc] = *(const short8*)(Q + bofs
                + (size_t)(q0 + qw*32 + qi*16 + lr) * DIM + dh*256 + kc*32 + lg*8);

    f32x4 zero = {0.f, 0.f, 0.f, 0.f};
    f32x4 o[2][16];
    #pragma unroll
    for (int qi = 0; qi < 2; ++qi)
        #pragma unroll
        for (int df = 0; df < 16; ++df) o[qi][df] = zero;
    float mreg[2][4], lreg[2][4];
    #pragma unroll
    for (int qi = 0; qi < 2; ++qi)
        #pragma unroll
        for (int r = 0; r < 4; ++r) { mreg[qi][r] = -1e30f; lreg[qi][r] = 0.f; }

    for (int t = 0; t < T; ++t) {
        int k0 = cstart + t * 32;
        __syncthreads();                       // prev-tile LDS reads done
        // stage Vt tile (32 KB): linear LDS dest, pre-swizzled global source
        #pragma unroll
        for (int rds = 0; rds < 8; ++rds) {
            int tt = tid + rds * 256;
            int d = tt >> 2, osw = tt & 3, oct = osw ^ (d & 3);
            gload16(Vt + vofs + (size_t)d * SEQ + k0 + oct * 8, vt_s + tt * 8);
        }
        // QK^T partial over our 256-dim half; K fragments direct from global (L2)
        f32x4 ss[2][2];
        ss[0][0] = zero; ss[0][1] = zero; ss[1][0] = zero; ss[1][1] = zero;
        #pragma unroll
        for (int kf = 0; kf < 2; ++kf) {
            const short* kr = K + bofs + (size_t)(k0 + kf*16 + lr) * DIM + dh*256 + lg*8;
            #pragma unroll
            for (int kc = 0; kc < 8; ++kc) {
                short8 kk = *(const short8*)(kr + kc*32);
                ss[0][kf] = __builtin_amdgcn_mfma_f32_16x16x32_bf16(qf[0][kc], kk, ss[0][kf], 0, 0, 0);
                ss[1][kf] = __builtin_amdgcn_mfma_f32_16x16x32_bf16(qf[1][kc], kk, ss[1][kf], 0, 0, 0);
            }
        }
        if (dh == 0) {
            #pragma unroll
            for (int qi = 0; qi < 2; ++qi)
                #pragma unroll
                for (int kf = 0; kf < 2; ++kf)
                    *(f32x4*)&part_s[qw][qi][kf][lane*4] = ss[qi][kf];
        }
        asm volatile("s_waitcnt vmcnt(0)");    // Vt DMA complete before barrier
        __syncthreads();                       // partials + Vt visible
        if (dh == 1) {
            #pragma unroll
            for (int qi = 0; qi < 2; ++qi) {
                #pragma unroll
                for (int kf = 0; kf < 2; ++kf) {
                    f32x4 pp = *(const f32x4*)&part_s[qw][qi][kf][lane*4];
                    #pragma unroll
                    for (int r = 0; r < 4; ++r)
                        ss[qi][kf][r] = (ss[qi][kf][r] + pp[r]) * scale;
                }
                if (causal) {
                    #pragma unroll
                    for (int kf = 0; kf < 2; ++kf) {
                        int colg = k0 + kf*16 + lr;
                        #pragma unroll
                        for (int r = 0; r < 4; ++r)
                            if (colg > q0 + qw*32 + qi*16 + lg*4 + r) ss[qi][kf][r] = -1e30f;
                    }
                }
                float tm[4];
                #pragma unroll
                for (int r = 0; r < 4; ++r) {
                    float v = fmaxf(ss[qi][0][r], ss[qi][1][r]);
                    v = fmaxf(v, __shfl_xor(v, 1));
                    v = fmaxf(v, __shfl_xor(v, 2));
                    v = fmaxf(v, __shfl_xor(v, 4));
                    v = fmaxf(v, __shfl_xor(v, 8));
                    tm[r] = v;
                }
                #pragma unroll
                for (int r = 0; r < 4; ++r) {
                    float nm = fmaxf(mreg[qi][r], tm[r]);
                    float fr = __expf(mreg[qi][r] - nm);
                    mreg[qi][r] = nm;
                    float p0 = __expf(ss[qi][0][r] - nm);
                    float p1 = __expf(ss[qi][1][r] - nm);
                    ss[qi][0][r] = p0; ss[qi][1][r] = p1;
                    float psum = p0 + p1;
                    psum += __shfl_xor(psum, 1);
                    psum += __shfl_xor(psum, 2);
                    psum += __shfl_xor(psum, 4);
                    psum += __shfl_xor(psum, 8);
                    lreg[qi][r] = lreg[qi][r] * fr + psum;
                    int row = lg*4 + r;
                    if (lr == 0) f_s[qw*32 + qi*16 + row] = fr;
                    #pragma unroll
                    for (int kf = 0; kf < 2; ++kf) {
                        int oct = kf*2 + (lr >> 3);
                        p_s[qw][qi][row*32 + ((oct ^ (row & 3)) << 3) + (lr & 7)] = bf16b(ss[qi][kf][r]);
                    }
                }
            }
        }
        __syncthreads();                       // P + fr visible
        float fv[2][4];
        bool nr = false;
        #pragma unroll
        for (int qi = 0; qi < 2; ++qi)
            #pragma unroll
            for (int r = 0; r < 4; ++r) {
                fv[qi][r] = f_s[qw*32 + qi*16 + lg*4 + r];
                nr |= (fv[qi][r] != 1.0f);
            }
        if (__any(nr)) {
            #pragma unroll
            for (int qi = 0; qi < 2; ++qi)
                #pragma unroll
                for (int df = 0; df < 16; ++df)
                    #pragma unroll
                    for (int r = 0; r < 4; ++r) o[qi][df][r] *= fv[qi][r];
        }
        short8 pa[2];
        #pragma unroll
        for (int qi = 0; qi < 2; ++qi)
            pa[qi] = *(const short8*)&p_s[qw][qi][lr*32 + ((lg ^ (lr & 3)) << 3)];
        #pragma unroll
        for (int df = 0; df < 16; ++df) {
            int d = dh*256 + df*16 + lr;
            short8 vv = *(const short8*)(vt_s + d*32 + ((lg ^ (d & 3)) << 3));
            o[0][df] = __builtin_amdgcn_mfma_f32_16x16x32_bf16(pa[0], vv, o[0][df], 0, 0, 0);
            o[1][df] = __builtin_amdgcn_mfma_f32_16x16x32_bf16(pa[1], vv, o[1][df], 0, 0, 0);
        }
    }

    // epilogue: write unnormalized o in fragment layout (coalesced 8B/lane), m/l per row
    #pragma unroll
    for (int qi = 0; qi < 2; ++qi) {
        size_t base = (((((size_t)(b*4 + c)*64 + j)*2 + dh)*2 + qw)*2 + qi) * 4096;
        #pragma unroll
        for (int df = 0; df < 16; ++df) {
            short4v pk;
            #pragma unroll
            for (int r = 0; r < 4; ++r) pk[r] = bf16b(o[qi][df][r]);
            *(short4v*)(Opart + base + df*256 + lane*4) = pk;
        }
    }
    if (dh == 1 && lr == 0) {
        #pragma unroll
        for (int qi = 0; qi < 2; ++qi)
            #pragma unroll
            for (int r = 0; r < 4; ++r) {
                int rowg = q0 + qw*32 + qi*16 + lg*4 + r;
                Mpart[(size_t)(b*4 + c)*SEQ + rowg] = mreg[qi][r];
                Lpart[(size_t)(b*4 + c)*SEQ + rowg] = lreg[qi][r];
            }
    }
}

// ---------------------------------------------------------------- merge chunk partials
// grid (j 64, dh 2, b 2); mode1: attb bf16 write; mode2: outf f32 accumulate (gated)
__global__ __launch_bounds__(256) void attn_merge(
        const short* __restrict__ Opart, const float* __restrict__ Mpart,
        const float* __restrict__ Lpart, short* __restrict__ attb,
        float* __restrict__ outf, const float* __restrict__ gate, int causal)
{
    if (gate && gate[0] == 0.0f) return;
    __shared__ float wts[4][64];
    int j = blockIdx.x, dh = blockIdx.y, b = blockIdx.z;
    int tid = threadIdx.x;
    if (tid < 64) {
        int rg = j*64 + tid;
        int nc = causal ? min(4, rg / CHUNK + 1) : 4;
        float M = -1e30f;
        for (int c = 0; c < nc; ++c)
            M = fmaxf(M, Mpart[(size_t)(b*4 + c)*SEQ + rg]);
        float L = 0.f;
        for (int c = 0; c < nc; ++c)
            L += Lpart[(size_t)(b*4 + c)*SEQ + rg] * __expf(Mpart[(size_t)(b*4 + c)*SEQ + rg] - M);
        float invL = 1.0f / L;
        for (int c = 0; c < 4; ++c)
            wts[c][tid] = (c < nc) ? __expf(Mpart[(size_t)(b*4 + c)*SEQ + rg] - M) * invL : 0.0f;
    }
    __syncthreads();
    int wv = tid >> 6, lane = tid & 63, lg = lane >> 4, lr = lane & 15;
    int qw = wv >> 1, qi = wv & 1;
    #pragma unroll 4
    for (int df = 0; df < 16; ++df) {
        float acc[4] = {0.f, 0.f, 0.f, 0.f};
        #pragma unroll
        for (int c = 0; c < 4; ++c) {
            size_t idx = (((((size_t)(b*4 + c)*64 + j)*2 + dh)*2 + qw)*2 + qi)*4096 + df*256 + lane*4;
            short4v v = *(const short4v*)(Opart + idx);
            #pragma unroll
            for (int r = 0; r < 4; ++r)
                acc[r] += wts[c][qw*32 + qi*16 + lg*4 + r] * bf16f(v[r]);
        }
        #pragma unroll
        for (int r = 0; r < 4; ++r) {
            int rowg = j*64 + qw*32 + qi*16 + lg*4 + r;
            int d = dh*256 + df*16 + lr;
            size_t oidx = (size_t)b*SEQ*DIM + (size_t)rowg*DIM + d;
            if (attb) attb[oidx] = bf16b(acc[r]);
            else      outf[oidx] += acc[r];
        }
    }
}

// ---------------------------------------------------------------- last-row scores (bf16 in)
__global__ __launch_bounds__(256) void lastrow_scores(const short* __restrict__ Q,
        const short* __restrict__ K, float* __restrict__ slast)
{
    __shared__ float q_l[DIM];
    int b = blockIdx.y;
    int m = blockIdx.x * 256 + threadIdx.x;
    for (int i = threadIdx.x; i < DIM; i += 256)
        q_l[i] = bf16f(Q[((size_t)b*SEQ + SEQ-1)*DIM + i]);
    __syncthreads();
    const short* kr = K + ((size_t)b*SEQ + m) * DIM;
    float s = 0.f;
    for (int d = 0; d < DIM; d += 8) {
        short8 k8 = *(const short8*)(kr + d);
        #pragma unroll
        for (int j = 0; j < 8; ++j) s += q_l[d + j] * bf16f(k8[j]);
    }
    slast[(size_t)b*SEQ + m] = s * RSQRT_D;
}

// ---------------------------------------------------------------- entropy of last-row softmax
__global__ __launch_bounds__(256) void entropy_kernel(const float* __restrict__ slast,
        float* __restrict__ H)
{
    __shared__ float sm[4];
    int b = blockIdx.x, t = threadIdx.x;
    const float* s = slast + (size_t)b * SEQ;
    float v[16];
    float mx = -1e30f;
    #pragma unroll
    for (int j = 0; j < 16; ++j) { v[j] = s[t + j*256]; mx = fmaxf(mx, v[j]); }
    #pragma unroll
    for (int o = 32; o; o >>= 1) mx = fmaxf(mx, __shfl_xor(mx, o));
    __syncthreads();
    if ((t & 63) == 0) sm[t >> 6] = mx;
    __syncthreads();
    mx = fmaxf(fmaxf(sm[0], sm[1]), fmaxf(sm[2], sm[3]));
    float se = 0.f;
    #pragma unroll
    for (int j = 0; j < 16; ++j) { v[j] = expf(v[j] - mx); se += v[j]; }
    se = blk_sum256(se, sm);
    float inv = 1.0f / se;
    float h = 0.f;
    #pragma unroll
    for (int j = 0; j < 16; ++j) {
        float p = fmaxf(v[j] * inv, 1e-9f);
        h -= p * logf(p);
    }
    h = blk_sum256(h, sm);
    if (t == 0) H[b] = h;
}

// ---------------------------------------------------------------- K mean partials (bf16 in)
__global__ __launch_bounds__(256) void krep_partial(const short* __restrict__ K,
        float* __restrict__ part)
{
    int b = blockIdx.y, j = blockIdx.x, t = threadIdx.x;
    size_t base = ((size_t)b*SEQ + (size_t)j*64) * DIM;
    float s0 = 0.f, s1 = 0.f;
    for (int r = 0; r < 64; ++r) {
        s0 += bf16f(K[base + (size_t)r*DIM + t]);
        s1 += bf16f(K[base + (size_t)r*DIM + t + 256]);
    }
    size_t o = (size_t)(b*64 + j) * DIM;
    part[o + t] = s0; part[o + t + 256] = s1;
}

// ---------------------------------------------------------------- gate scalar kernel
__global__ __launch_bounds__(256) void scalar_kernel(const short* __restrict__ Qb,
        const float* __restrict__ part, const float* __restrict__ Hent,
        float* __restrict__ gsc)
{
    __shared__ float sm[4];
    __shared__ float sims[BATCH];
    int t = threadIdx.x;
    float qv0 = 0.5f*(bf16f(Qb[((size_t)0*SEQ + SEQ-1)*DIM + t])     + bf16f(Qb[((size_t)1*SEQ + SEQ-1)*DIM + t]));
    float qv1 = 0.5f*(bf16f(Qb[((size_t)0*SEQ + SEQ-1)*DIM + t+256]) + bf16f(Qb[((size_t)1*SEQ + SEQ-1)*DIM + t+256]));
    for (int b = 0; b < BATCH; ++b) {
        float k0 = 0.f, k1 = 0.f;
        for (int j = 0; j < 64; ++j) {
            k0 += part[(size_t)(b*64+j)*DIM + t];
            k1 += part[(size_t)(b*64+j)*DIM + t + 256];
        }
        k0 *= (1.0f/SEQ); k1 *= (1.0f/SEQ);
        float num = blk_sum256(qv0*k0 + qv1*k1, sm);
        float qq  = blk_sum256(qv0*qv0 + qv1*qv1, sm);
        float kk  = blk_sum256(k0*k0 + k1*k1, sm);
        if (t == 0) {
            float na = fmaxf(sqrtf(qq), 1e-8f);
            float nb = fmaxf(sqrtf(kk), 1e-8f);
            sims[b] = num / (na * nb);
        }
        __syncthreads();
    }
    if (t == 0) {
        float H0 = Hent[0], H1 = Hent[1];
        float mn = fminf(H0, H1), mx = fmaxf(H0, H1);
        float den = (mx - mn) + 1e-9f;
        float Hm = 0.5f*((H0 - mn)/den + (H1 - mn)/den);
        float T  = 0.6f + (1.6f - 0.6f) * Hm;
        float th = 0.9f - (0.9f - 0.5f) * Hm;
        float s  = 0.5f * (sims[0] + sims[1]);
        gsc[0] = (s >= th) ? 1.0f : 0.0f;
        gsc[1] = 1.0f / (sqrtf((float)DIM) * T);
    }
}

// ---------------------------------------------------------------- launch
extern "C" void kernel_launch(void* const* d_in, const int* in_sizes, int n_in,
                              void* d_out, int out_size, void* d_ws, size_t ws_size,
                              hipStream_t stream)
{
    (void)in_sizes; (void)n_in; (void)out_size; (void)ws_size;
    const float* x     = (const float*)d_in[0];
    const float* Wq    = (const float*)d_in[1];
    const float* Wk    = (const float*)d_in[2];
    const float* Wv    = (const float*)d_in[3];
    const float* Wp    = (const float*)d_in[4];
    const float* W1    = (const float*)d_in[5];
    const float* b1    = (const float*)d_in[6];
    const float* W2    = (const float*)d_in[7];
    const float* b2    = (const float*)d_in[8];
    const float* gamma = (const float*)d_in[9];
    const float* beta  = (const float*)d_in[10];
    float* out = (float*)d_out;

    const size_t NT = (size_t)NROWS * DIM;   // 4,194,304
    short* bws   = (short*)d_ws;
    short* Qbf   = bws;                      // 4M
    short* Kbf   = Qbf + NT;                 // 4M
    short* Vt    = Kbf + NT;                 // 4M
    short* att   = Vt + NT;                  // 4M
    short* Wqb   = att + NT;
    short* Wkb   = Wqb + 262144;
    short* Wvb   = Wkb + 262144;
    short* Wpb   = Wvb + 262144;
    short* W1b   = Wpb + 262144;
    short* W2b   = W1b + 1048576;
    float* slast = (float*)(W2b + 1048576);  // 8192
    float* Hent  = slast + 8192;             // 8
    float* kpart = Hent + 8;                 // 2*64*512 = 65536
    float* gsc   = kpart + 65536;            // 8
    float* Mpart = gsc + 8;                  // 8*4096
    float* Lpart = Mpart + 32768;            // 8*4096
    short* xn_bf = (short*)(Lpart + 32768);  // 4M (dead during attention)
    short* h1    = xn_bf + NT;               // 8M (dead during attention)
    short* Opart = xn_bf;                    // 16M shorts aliased: xn(4M)+h1(8M)+spare(4M)
    // total ws use ≈ 69 MB

    // weights -> bf16
    f2bf<<<128, 256, 0, stream>>>(Wq, Wqb, 32768);
    f2bf<<<128, 256, 0, stream>>>(Wk, Wkb, 32768);
    f2bf<<<128, 256, 0, stream>>>(Wv, Wvb, 32768);
    f2bf<<<128, 256, 0, stream>>>(Wp, Wpb, 32768);
    f2bf<<<512, 256, 0, stream>>>(W1, W1b, 131072);
    f2bf<<<512, 256, 0, stream>>>(W2, W2b, 131072);

    ln_kernel<<<NROWS/4, 256, 0, stream>>>(x, gamma, beta, xn_bf);

    dim3 gproj(DIM/128, NROWS/128);
    gemm_bf16<<<gproj, 256, 0, stream>>>(xn_bf, Wqb, nullptr, nullptr, nullptr, Qbf, NROWS, DIM, DIM, 0, 0);
    gemm_bf16<<<gproj, 256, 0, stream>>>(xn_bf, Wkb, nullptr, nullptr, nullptr, Kbf, NROWS, DIM, DIM, 0, 0);
    gemm_bf16<<<gproj, 256, 0, stream>>>(xn_bf, Wvb, nullptr, nullptr, nullptr, h1,  NROWS, DIM, DIM, 0, 0);
    vtrans<<<dim3(SEQ/64, DIM/64, BATCH), 256, 0, stream>>>(h1, Vt);
    // xn_bf and h1 are now dead -> Opart may overwrite them

    attn_part<<<dim3(64, 4, BATCH), 256, 0, stream>>>(Qbf, Kbf, Vt, Opart, Mpart, Lpart,
                                                      RSQRT_D, nullptr, nullptr, 1);
    attn_merge<<<dim3(64, 2, BATCH), 256, 0, stream>>>(Opart, Mpart, Lpart, att, nullptr,
                                                       nullptr, 1);

    lastrow_scores<<<dim3(SEQ/256, BATCH), 256, 0, stream>>>(Qbf, Kbf, slast);
    entropy_kernel<<<BATCH, 256, 0, stream>>>(slast, Hent);

    // ctx = x + att @ Wp^T   (fp32 into d_out)
    gemm_bf16<<<gproj, 256, 0, stream>>>(att, Wpb, nullptr, x, out, nullptr, NROWS, DIM, DIM, 0, 0);

    // h = LN(ctx) -> xn_bf (Opart dead after merge1)
    ln_kernel<<<NROWS/4, 256, 0, stream>>>(out, gamma, beta, xn_bf);

    // FFN: 2 chunks of 4096 rows
    for (int c = 0; c < 2; ++c) {
        const short* hc = xn_bf + (size_t)c * 4096 * DIM;
        float* oc = out + (size_t)c * 4096 * DIM;
        gemm_bf16<<<dim3(FF/128, 4096/128), 256, 0, stream>>>(hc, W1b, b1, nullptr, nullptr, h1,
                                                              4096, FF, DIM, 1, 0);
        gemm_bf16<<<dim3(DIM/128, 4096/128), 256, 0, stream>>>(h1, W2b, b2, nullptr, oc, nullptr,
                                                               4096, DIM, FF, 0, 1);
    }

    krep_partial<<<dim3(64, BATCH), 256, 0, stream>>>(Kbf, kpart);
    scalar_kernel<<<1, 256, 0, stream>>>(Qbf, kpart, Hent, gsc);

    // gated re-attention (non-causal, temperature): xn_bf/h1 dead again -> reuse Opart
    attn_part<<<dim3(64, 4, BATCH), 256, 0, stream>>>(Qbf, Kbf, Vt, Opart, Mpart, Lpart,
                                                      0.0f, gsc + 1, gsc, 0);
    attn_merge<<<dim3(64, 2, BATCH), 256, 0, stream>>>(Opart, Mpart, Lpart, nullptr, out,
                                                       gsc, 0);
}

// Round 4
// 507.211 us; speedup vs baseline: 7.3128x; 1.4485x over previous
//
#include <hip/hip_runtime.h>
#include <math.h>

#define BATCH 2
#define SEQ 4096
#define DIM 512
#define FF 2048
#define NROWS (BATCH*SEQ)
#define KT 32
#define RSQRT_D 0.044194173824159216f  /* 1/sqrt(512) */

typedef __attribute__((ext_vector_type(8))) short short8;
typedef __attribute__((ext_vector_type(4))) short short4v;
typedef __attribute__((ext_vector_type(4))) float f32x4;

// ---------------------------------------------------------------- helpers
__device__ __forceinline__ float gelu_f(float v) {
    return 0.5f * v * (1.0f + erff(v * 0.70710678118654752440f));
}
__device__ __forceinline__ short bf16b(float x) {
    union { float f; unsigned u; } c; c.f = x;
    unsigned r = (c.u + 0x7FFFu + ((c.u >> 16) & 1u)) >> 16;
    return (short)r;
}
__device__ __forceinline__ float bf16f(short h) {
    union { unsigned u; float f; } c; c.u = ((unsigned)(unsigned short)h) << 16;
    return c.f;
}
__device__ __forceinline__ void gload16(const void* g, void* l) {
    __builtin_amdgcn_global_load_lds(
        (const __attribute__((address_space(1))) unsigned int*)g,
        (__attribute__((address_space(3))) unsigned int*)l, 16, 0, 0);
}
__device__ __forceinline__ float blk_sum256(float v, volatile float* sm) {
    #pragma unroll
    for (int o = 32; o; o >>= 1) v += __shfl_xor(v, o);
    __syncthreads();
    if ((threadIdx.x & 63) == 0) sm[threadIdx.x >> 6] = v;
    __syncthreads();
    return sm[0] + sm[1] + sm[2] + sm[3];
}

// ---------------------------------------------------------------- f32 -> bf16 convert
__global__ __launch_bounds__(256) void f2bf(const float* __restrict__ in,
                                            short* __restrict__ out, int n8)
{
    int i = blockIdx.x * 256 + threadIdx.x;
    if (i >= n8) return;
    const float4* p = (const float4*)(in + (size_t)i * 8);
    float4 a = p[0], b = p[1];
    short8 r;
    r[0]=bf16b(a.x); r[1]=bf16b(a.y); r[2]=bf16b(a.z); r[3]=bf16b(a.w);
    r[4]=bf16b(b.x); r[5]=bf16b(b.y); r[6]=bf16b(b.z); r[7]=bf16b(b.w);
    *(short8*)(out + (size_t)i * 8) = r;
}

// ---------------------------------------------------------------- layernorm (f32 in, bf16 out)
__global__ __launch_bounds__(256) void ln_kernel(const float* __restrict__ x,
        const float* __restrict__ g, const float* __restrict__ be,
        short* __restrict__ o)
{
    int row  = blockIdx.x * 4 + (threadIdx.x >> 6);
    int lane = threadIdx.x & 63;
    const float4* xr = (const float4*)(x + (size_t)row * DIM);
    float4 v0 = xr[lane*2], v1 = xr[lane*2+1];
    float s = v0.x+v0.y+v0.z+v0.w + v1.x+v1.y+v1.z+v1.w;
    #pragma unroll
    for (int off = 32; off; off >>= 1) s += __shfl_xor(s, off);
    float mu = s * (1.0f/DIM);
    float d[8] = {v0.x-mu, v0.y-mu, v0.z-mu, v0.w-mu, v1.x-mu, v1.y-mu, v1.z-mu, v1.w-mu};
    float q = 0.f;
    #pragma unroll
    for (int j = 0; j < 8; ++j) q += d[j]*d[j];
    #pragma unroll
    for (int off = 32; off; off >>= 1) q += __shfl_xor(q, off);
    float rs = rsqrtf(q * (1.0f/DIM) + 1e-5f);
    const float4* g4 = (const float4*)g;
    const float4* b4 = (const float4*)be;
    float4 ga = g4[lane*2], gb = g4[lane*2+1];
    float4 ba = b4[lane*2], bb = b4[lane*2+1];
    float gv[8] = {ga.x,ga.y,ga.z,ga.w, gb.x,gb.y,gb.z,gb.w};
    float bv[8] = {ba.x,ba.y,ba.z,ba.w, bb.x,bb.y,bb.z,bb.w};
    short8 r;
    #pragma unroll
    for (int j = 0; j < 8; ++j) r[j] = bf16b(d[j]*rs*gv[j] + bv[j]);
    *(short8*)(o + (size_t)row * DIM + lane*8) = r;
}

// ---------------------------------------------------------------- bf16 MFMA GEMM (unchanged)
__global__ __launch_bounds__(256) void gemm_bf16(
        const short* __restrict__ A, const short* __restrict__ W,
        const float* __restrict__ bias, const float* __restrict__ res,
        float* __restrict__ Cf, short* __restrict__ Cb,
        int M, int N, int K, int act, int accum)
{
    __shared__ short As[128*32];
    __shared__ short Ws[128*32];
    int tid = threadIdx.x;
    int m0 = blockIdx.y * 128, n0 = blockIdx.x * 128;
    int w = tid >> 6, lane = tid & 63;
    int wr = (w >> 1) * 64, wc = (w & 1) * 64;
    int lr = lane & 15, lg = lane >> 4;
    int srow = tid >> 2, skoff = (tid & 3) * 8;
    f32x4 acc[4][4];
    f32x4 zero = {0.f, 0.f, 0.f, 0.f};
    #pragma unroll
    for (int i = 0; i < 4; ++i)
        #pragma unroll
        for (int j = 0; j < 4; ++j) acc[i][j] = zero;

    for (int k0 = 0; k0 < K; k0 += 32) {
        __syncthreads();
        gload16(A + (size_t)(m0 + srow) * K + k0 + skoff,      As + tid*8);
        gload16(A + (size_t)(m0 + 64 + srow) * K + k0 + skoff, As + 2048 + tid*8);
        gload16(W + (size_t)(n0 + srow) * K + k0 + skoff,      Ws + tid*8);
        gload16(W + (size_t)(n0 + 64 + srow) * K + k0 + skoff, Ws + 2048 + tid*8);
        __syncthreads();
        short8 a[4], b[4];
        #pragma unroll
        for (int i = 0; i < 4; ++i) a[i] = *(const short8*)(As + (wr + i*16 + lr)*32 + lg*8);
        #pragma unroll
        for (int j = 0; j < 4; ++j) b[j] = *(const short8*)(Ws + (wc + j*16 + lr)*32 + lg*8);
        #pragma unroll
        for (int i = 0; i < 4; ++i)
            #pragma unroll
            for (int j = 0; j < 4; ++j)
                acc[i][j] = __builtin_amdgcn_mfma_f32_16x16x32_bf16(a[i], b[j], acc[i][j], 0, 0, 0);
    }

    #pragma unroll
    for (int i = 0; i < 4; ++i) {
        #pragma unroll
        for (int r = 0; r < 4; ++r) {
            size_t m = (size_t)m0 + wr + i*16 + lg*4 + r;
            #pragma unroll
            for (int j = 0; j < 4; ++j) {
                int n = n0 + wc + j*16 + lr;
                float v = acc[i][j][r];
                if (bias) v += bias[n];
                if (act)  v = gelu_f(v);
                if (res)  v += res[m * N + n];
                size_t idx = m * N + n;
                if (Cf) { if (accum) Cf[idx] += v; else Cf[idx] = v; }
                if (Cb) Cb[idx] = bf16b(v);
            }
        }
    }
}

// ---------------------------------------------------------------- bf16 tile transpose V[b][l][d] -> Vt[b][d][l]
__global__ __launch_bounds__(256) void vtrans(const short* __restrict__ V,
                                              short* __restrict__ Vt)
{
    __shared__ short t_s[64][72];
    int l0 = blockIdx.x * 64, d0 = blockIdx.y * 64, b = blockIdx.z;
    int t = threadIdx.x;
    const short* src = V + (size_t)b * SEQ * DIM;
    #pragma unroll
    for (int it = 0; it < 2; ++it) {
        int r = (t >> 3) + it * 32, c = (t & 7) * 8;
        *(short8*)&t_s[r][c] = *(const short8*)(src + (size_t)(l0 + r) * DIM + d0 + c);
    }
    __syncthreads();
    short* dst = Vt + (size_t)b * DIM * SEQ;
    #pragma unroll
    for (int it = 0; it < 2; ++it) {
        int r = (t >> 3) + it * 32, c = (t & 7) * 8;
        short8 v;
        #pragma unroll
        for (int j = 0; j < 8; ++j) v[j] = t_s[c + j][r];
        *(short8*)(dst + (size_t)(d0 + r) * SEQ + l0 + c) = v;
    }
}

// ---------------------------------------------------------------- attention v4
// 8 waves (512 thr): wave = (rg 0..3 row-group of 16 rows, dh 0..1 dim-half).
// Both dh waves redundantly compute full-D QK (no exchange, no divergence);
// each accumulates o for its 256-dim half. K+Vt LDS-staged, double-buffered,
// XOR-swizzled via pre-swizzled global source. Defer-max online softmax.
// Grid: 256 blocks = 32 pairs (j, 63-j) x 4 chunks x 2 batches, 1 block/CU.
__global__ __launch_bounds__(512, 2) void attn_v4(
        const short* __restrict__ Q, const short* __restrict__ K,
        const short* __restrict__ Vt, short* __restrict__ Opart,
        float* __restrict__ Mpart, float* __restrict__ Lpart,
        float scale, const float* __restrict__ scale_ptr,
        const float* __restrict__ gate, int causal)
{
    if (gate && gate[0] == 0.0f) return;
    if (scale_ptr) scale = scale_ptr[0];
    extern __shared__ short lds[];
    short* k_s = lds;            // [2][32 rows][512 dims]  64 KB
    short* v_s = lds + 32768;    // [2][512 d][32 keys]     64 KB (swizzled slots)
    short* p_s = lds + 65536;    // [8 waves][16 rows][32]   8 KB

    int tid = threadIdx.x, w = tid >> 6, lane = tid & 63;
    int rg = w >> 1, dh = w & 1;
    int lr = lane & 15, lg = lane >> 4;

    int bid = blockIdx.x;
    int cb = bid & 7;                 // XCD slot = (chunk, batch)
    int c  = cb & 3, b = cb >> 2;
    int ip = bid >> 3;                // pair index 0..31
    int jj0 = ip, jj1 = 63 - ip;
    int TA = causal ? 2*(ip+1)  : 128;
    int TB = causal ? 2*(64-ip) : 128;
    int Ttot = TA + TB;
    int s0 = (Ttot * c) >> 2, s1 = (Ttot * (c+1)) >> 2;

    size_t bofs = (size_t)b * SEQ * DIM;
    size_t vofs = (size_t)b * DIM * SEQ;
    f32x4 zero = {0.f, 0.f, 0.f, 0.f};

    for (int sg = 0; sg < 2; ++sg) {
        int j  = sg ? jj1 : jj0;
        int ta = sg ? (max(s0, TA) - TA) : s0;
        int tb = sg ? (s1 - TA)          : min(s1, TA);
        if (ta >= tb) continue;
        int qw0 = j*64 + rg*16;

        short8 qf[16];
        #pragma unroll
        for (int kc = 0; kc < 16; ++kc)
            qf[kc] = *(const short8*)(Q + bofs + (size_t)(qw0 + lr)*DIM + kc*32 + lg*8);

        f32x4 o[16];
        #pragma unroll
        for (int df = 0; df < 16; ++df) o[df] = zero;
        float mreg[4] = {-1e30f,-1e30f,-1e30f,-1e30f};
        float lreg[4] = {0.f,0.f,0.f,0.f};
        int rowg[4];
        #pragma unroll
        for (int r = 0; r < 4; ++r) rowg[r] = qw0 + lg*4 + r;

        int cur = 0;
        {   // prologue: stage tile ta into buf 0
            int k0s = ta * KT;
            #pragma unroll
            for (int s4 = 0; s4 < 4; ++s4) {
                int slot = tid + s4*512;
                int row = slot >> 6, cg = slot & 63;
                gload16(K + bofs + (size_t)(k0s + row)*DIM + ((cg ^ (row & 7)) << 3),
                        k_s + slot*8);
                int dpair = slot >> 3, low = slot & 7;
                int d = dpair*2 + (low & 1);
                int kg = (low >> 1) ^ (dpair & 3);
                gload16(Vt + vofs + (size_t)d*SEQ + k0s + kg*8,
                        v_s + slot*8);
            }
        }
        __syncthreads();   // implicit vmcnt drain -> buffers ready

        for (int t = ta; t < tb; ++t) {
            int k0 = t * KT;
            if (t + 1 < tb) {      // prefetch next tile into buf cur^1
                int k0s = (t + 1) * KT;
                int bo = (cur ^ 1) * 16384;
                #pragma unroll
                for (int s4 = 0; s4 < 4; ++s4) {
                    int slot = tid + s4*512;
                    int row = slot >> 6, cg = slot & 63;
                    gload16(K + bofs + (size_t)(k0s + row)*DIM + ((cg ^ (row & 7)) << 3),
                            k_s + bo + slot*8);
                    int dpair = slot >> 3, low = slot & 7;
                    int d = dpair*2 + (low & 1);
                    int kg = (low >> 1) ^ (dpair & 3);
                    gload16(Vt + vofs + (size_t)d*SEQ + k0s + kg*8,
                            v_s + bo + slot*8);
                }
            }
            // ---- QK^T (full D, redundant across dh)
            f32x4 ss[2];
            ss[0] = zero; ss[1] = zero;
            const short* kb = k_s + cur*16384;
            #pragma unroll
            for (int kc = 0; kc < 16; ++kc) {
                #pragma unroll
                for (int kf = 0; kf < 2; ++kf) {
                    int row = kf*16 + lr;
                    short8 kk = *(const short8*)(kb + row*512 + (((kc*4 + lg) ^ (row & 7)) << 3));
                    ss[kf] = __builtin_amdgcn_mfma_f32_16x16x32_bf16(qf[kc], kk, ss[kf], 0, 0, 0);
                }
            }
            // ---- scale + causal mask
            bool needmask = causal && (k0 + KT - 1 > qw0);
            #pragma unroll
            for (int kf = 0; kf < 2; ++kf) {
                int key = k0 + kf*16 + lr;
                #pragma unroll
                for (int r = 0; r < 4; ++r) {
                    float sv = ss[kf][r] * scale;
                    if (needmask && key > rowg[r]) sv = -1e30f;
                    ss[kf][r] = sv;
                }
            }
            // ---- defer-max online softmax
            float pm[4];
            bool tg = false;
            #pragma unroll
            for (int r = 0; r < 4; ++r) {
                pm[r] = fmaxf(ss[0][r], ss[1][r]);
                tg |= (pm[r] > mreg[r]);
            }
            if (__any(tg)) {
                #pragma unroll
                for (int r = 0; r < 4; ++r) {
                    float v = pm[r];
                    v = fmaxf(v, __shfl_xor(v, 1));
                    v = fmaxf(v, __shfl_xor(v, 2));
                    v = fmaxf(v, __shfl_xor(v, 4));
                    v = fmaxf(v, __shfl_xor(v, 8));
                    float nm = fmaxf(mreg[r], v);
                    float fr = __expf(mreg[r] - nm);
                    mreg[r] = nm;
                    lreg[r] *= fr;
                    #pragma unroll
                    for (int df = 0; df < 16; ++df) o[df][r] *= fr;
                }
            }
            // ---- P = exp(s - m), pack to own LDS region, reload as A-frag
            #pragma unroll
            for (int kf = 0; kf < 2; ++kf) {
                #pragma unroll
                for (int r = 0; r < 4; ++r) {
                    float sv = ss[kf][r];
                    float p = (sv < -1e29f) ? 0.0f : __expf(sv - mreg[r]);
                    lreg[r] += p;
                    p_s[w*512 + (lg*4 + r)*32 + kf*16 + lr] = bf16b(p);
                }
            }
            short8 pa = *(const short8*)(p_s + w*512 + lr*32 + lg*8);
            // ---- PV (own d-half)
            const short* vb = v_s + cur*16384;
            #pragma unroll
            for (int df = 0; df < 16; ++df) {
                int d = dh*256 + df*16 + lr;
                int slot16 = (d >> 1)*8 + (((lg ^ ((d >> 1) & 3)) << 1) | (d & 1));
                short8 vv = *(const short8*)(vb + slot16*8);
                o[df] = __builtin_amdgcn_mfma_f32_16x16x32_bf16(pa, vv, o[df], 0, 0, 0);
            }
            __syncthreads();   // full drain: prefetch done, buffers swappable
            cur ^= 1;
        }

        // ---- flush partials for (b, j, c)
        #pragma unroll
        for (int r = 0; r < 4; ++r) {
            float v = lreg[r];
            v += __shfl_xor(v, 1);
            v += __shfl_xor(v, 2);
            v += __shfl_xor(v, 4);
            v += __shfl_xor(v, 8);
            lreg[r] = v;
        }
        int slot = (b*64 + j)*4 + c;
        size_t obase = ((size_t)slot*8 + w) * 4096;
        #pragma unroll
        for (int df = 0; df < 16; ++df) {
            short4v pk;
            #pragma unroll
            for (int r = 0; r < 4; ++r) pk[r] = bf16b(o[df][r]);
            *(short4v*)(Opart + obase + df*256 + lane*4) = pk;
        }
        if (dh == 0 && lr == 0) {
            #pragma unroll
            for (int r = 0; r < 4; ++r) {
                Mpart[slot*64 + rg*16 + lg*4 + r] = mreg[r];
                Lpart[slot*64 + rg*16 + lg*4 + r] = lreg[r];
            }
        }
    }
}

// ---------------------------------------------------------------- merge chunk partials
// grid (j 64, dh 2, b 2); mode1: attb bf16 write; mode2: outf f32 accumulate (gated)
__global__ __launch_bounds__(256) void attn_merge(
        const short* __restrict__ Opart, const float* __restrict__ Mpart,
        const float* __restrict__ Lpart, short* __restrict__ attb,
        float* __restrict__ outf, const float* __restrict__ gate, int causal)
{
    if (gate && gate[0] == 0.0f) return;
    __shared__ float wts[4][64];
    int j = blockIdx.x, dh = blockIdx.y, b = blockIdx.z;
    int tid = threadIdx.x;
    int ip = (j < 32) ? j : 63 - j;
    int TA = causal ? 2*(ip+1)  : 128;
    int TB = causal ? 2*(64-ip) : 128;
    int Ttot = TA + TB;
    int jstart = (j < 32) ? 0 : TA;
    int jend   = (j < 32) ? TA : Ttot;
    bool val[4];
    #pragma unroll
    for (int c = 0; c < 4; ++c) {
        int sc = (Ttot * c) >> 2, ec = (Ttot * (c+1)) >> 2;
        val[c] = (sc < jend) && (ec > jstart);
    }
    if (tid < 64) {
        float M = -1e30f;
        #pragma unroll
        for (int c = 0; c < 4; ++c)
            if (val[c]) M = fmaxf(M, Mpart[((b*64 + j)*4 + c)*64 + tid]);
        float L = 0.f;
        #pragma unroll
        for (int c = 0; c < 4; ++c)
            if (val[c]) L += Lpart[((b*64 + j)*4 + c)*64 + tid]
                           * __expf(Mpart[((b*64 + j)*4 + c)*64 + tid] - M);
        float invL = 1.0f / L;
        #pragma unroll
        for (int c = 0; c < 4; ++c)
            wts[c][tid] = val[c]
                ? __expf(Mpart[((b*64 + j)*4 + c)*64 + tid] - M) * invL : 0.0f;
    }
    __syncthreads();
    int wv = tid >> 6, lane = tid & 63, lg = lane >> 4, lr = lane & 15;
    int region = wv*2 + dh;
    #pragma unroll 4
    for (int df = 0; df < 16; ++df) {
        float acc[4] = {0.f, 0.f, 0.f, 0.f};
        #pragma unroll
        for (int c = 0; c < 4; ++c) {
            if (!val[c]) continue;
            size_t idx = ((size_t)((b*64 + j)*4 + c)*8 + region)*4096 + df*256 + lane*4;
            short4v v = *(const short4v*)(Opart + idx);
            #pragma unroll
            for (int r = 0; r < 4; ++r)
                acc[r] += wts[c][wv*16 + lg*4 + r] * bf16f(v[r]);
        }
        #pragma unroll
        for (int r = 0; r < 4; ++r) {
            int row = j*64 + wv*16 + lg*4 + r;
            int d = dh*256 + df*16 + lr;
            size_t oidx = (size_t)b*SEQ*DIM + (size_t)row*DIM + d;
            if (attb) attb[oidx] = bf16b(acc[r]);
            else      outf[oidx] += acc[r];
        }
    }
}

// ---------------------------------------------------------------- last-row scores (bf16 in)
__global__ __launch_bounds__(256) void lastrow_scores(const short* __restrict__ Q,
        const short* __restrict__ K, float* __restrict__ slast)
{
    __shared__ float q_l[DIM];
    int b = blockIdx.y;
    int m = blockIdx.x * 256 + threadIdx.x;
    for (int i = threadIdx.x; i < DIM; i += 256)
        q_l[i] = bf16f(Q[((size_t)b*SEQ + SEQ-1)*DIM + i]);
    __syncthreads();
    const short* kr = K + ((size_t)b*SEQ + m) * DIM;
    float s = 0.f;
    for (int d = 0; d < DIM; d += 8) {
        short8 k8 = *(const short8*)(kr + d);
        #pragma unroll
        for (int j = 0; j < 8; ++j) s += q_l[d + j] * bf16f(k8[j]);
    }
    slast[(size_t)b*SEQ + m] = s * RSQRT_D;
}

// ---------------------------------------------------------------- entropy of last-row softmax
__global__ __launch_bounds__(256) void entropy_kernel(const float* __restrict__ slast,
        float* __restrict__ H)
{
    __shared__ float sm[4];
    int b = blockIdx.x, t = threadIdx.x;
    const float* s = slast + (size_t)b * SEQ;
    float v[16];
    float mx = -1e30f;
    #pragma unroll
    for (int j = 0; j < 16; ++j) { v[j] = s[t + j*256]; mx = fmaxf(mx, v[j]); }
    #pragma unroll
    for (int o = 32; o; o >>= 1) mx = fmaxf(mx, __shfl_xor(mx, o));
    __syncthreads();
    if ((t & 63) == 0) sm[t >> 6] = mx;
    __syncthreads();
    mx = fmaxf(fmaxf(sm[0], sm[1]), fmaxf(sm[2], sm[3]));
    float se = 0.f;
    #pragma unroll
    for (int j = 0; j < 16; ++j) { v[j] = expf(v[j] - mx); se += v[j]; }
    se = blk_sum256(se, sm);
    float inv = 1.0f / se;
    float h = 0.f;
    #pragma unroll
    for (int j = 0; j < 16; ++j) {
        float p = fmaxf(v[j] * inv, 1e-9f);
        h -= p * logf(p);
    }
    h = blk_sum256(h, sm);
    if (t == 0) H[b] = h;
}

// ---------------------------------------------------------------- K mean partials (bf16 in)
__global__ __launch_bounds__(256) void krep_partial(const short* __restrict__ K,
        float* __restrict__ part)
{
    int b = blockIdx.y, j = blockIdx.x, t = threadIdx.x;
    size_t base = ((size_t)b*SEQ + (size_t)j*64) * DIM;
    float s0 = 0.f, s1 = 0.f;
    for (int r = 0; r < 64; ++r) {
        s0 += bf16f(K[base + (size_t)r*DIM + t]);
        s1 += bf16f(K[base + (size_t)r*DIM + t + 256]);
    }
    size_t o = (size_t)(b*64 + j) * DIM;
    part[o + t] = s0; part[o + t + 256] = s1;
}

// ---------------------------------------------------------------- gate scalar kernel
__global__ __launch_bounds__(256) void scalar_kernel(const short* __restrict__ Qb,
        const float* __restrict__ part, const float* __restrict__ Hent,
        float* __restrict__ gsc)
{
    __shared__ float sm[4];
    __shared__ float sims[BATCH];
    int t = threadIdx.x;
    float qv0 = 0.5f*(bf16f(Qb[((size_t)0*SEQ + SEQ-1)*DIM + t])     + bf16f(Qb[((size_t)1*SEQ + SEQ-1)*DIM + t]));
    float qv1 = 0.5f*(bf16f(Qb[((size_t)0*SEQ + SEQ-1)*DIM + t+256]) + bf16f(Qb[((size_t)1*SEQ + SEQ-1)*DIM + t+256]));
    for (int b = 0; b < BATCH; ++b) {
        float k0 = 0.f, k1 = 0.f;
        for (int j = 0; j < 64; ++j) {
            k0 += part[(size_t)(b*64+j)*DIM + t];
            k1 += part[(size_t)(b*64+j)*DIM + t + 256];
        }
        k0 *= (1.0f/SEQ); k1 *= (1.0f/SEQ);
        float num = blk_sum256(qv0*k0 + qv1*k1, sm);
        float qq  = blk_sum256(qv0*qv0 + qv1*qv1, sm);
        float kk  = blk_sum256(k0*k0 + k1*k1, sm);
        if (t == 0) {
            float na = fmaxf(sqrtf(qq), 1e-8f);
            float nb = fmaxf(sqrtf(kk), 1e-8f);
            sims[b] = num / (na * nb);
        }
        __syncthreads();
    }
    if (t == 0) {
        float H0 = Hent[0], H1 = Hent[1];
        float mn = fminf(H0, H1), mx = fmaxf(H0, H1);
        float den = (mx - mn) + 1e-9f;
        float Hm = 0.5f*((H0 - mn)/den + (H1 - mn)/den);
        float T  = 0.6f + (1.6f - 0.6f) * Hm;
        float th = 0.9f - (0.9f - 0.5f) * Hm;
        float s  = 0.5f * (sims[0] + sims[1]);
        gsc[0] = (s >= th) ? 1.0f : 0.0f;
        gsc[1] = 1.0f / (sqrtf((float)DIM) * T);
    }
}

// ---------------------------------------------------------------- launch
extern "C" void kernel_launch(void* const* d_in, const int* in_sizes, int n_in,
                              void* d_out, int out_size, void* d_ws, size_t ws_size,
                              hipStream_t stream)
{
    (void)in_sizes; (void)n_in; (void)out_size; (void)ws_size;
    const float* x     = (const float*)d_in[0];
    const float* Wq    = (const float*)d_in[1];
    const float* Wk    = (const float*)d_in[2];
    const float* Wv    = (const float*)d_in[3];
    const float* Wp    = (const float*)d_in[4];
    const float* W1    = (const float*)d_in[5];
    const float* b1    = (const float*)d_in[6];
    const float* W2    = (const float*)d_in[7];
    const float* b2    = (const float*)d_in[8];
    const float* gamma = (const float*)d_in[9];
    const float* beta  = (const float*)d_in[10];
    float* out = (float*)d_out;

    const size_t NT = (size_t)NROWS * DIM;   // 4,194,304
    short* bws   = (short*)d_ws;
    short* Qbf   = bws;                      // 4M
    short* Kbf   = Qbf + NT;                 // 4M
    short* Vt    = Kbf + NT;                 // 4M
    short* att   = Vt + NT;                  // 4M (also V pre-transpose temp)
    short* Wqb   = att + NT;
    short* Wkb   = Wqb + 262144;
    short* Wvb   = Wkb + 262144;
    short* Wpb   = Wvb + 262144;
    short* W1b   = Wpb + 262144;
    short* W2b   = W1b + 1048576;
    float* slast = (float*)(W2b + 1048576);  // 8192
    float* Hent  = slast + 8192;             // 8
    float* kpart = Hent + 8;                 // 65536
    float* gsc   = kpart + 65536;            // 8
    float* Mpart = gsc + 8;                  // 32768
    float* Lpart = Mpart + 32768;            // 32768
    short* xn_bf = (short*)(Lpart + 32768);  // 4M (dead during attention)
    short* h1    = xn_bf + NT;               // 8M (dead during attention)
    short* Opart = xn_bf;                    // 16M shorts: xn(4M)+h1(8M)+spare(4M)

    const int ATTN_LDS = 139264;             // 64K k + 64K v + 8K p
    hipFuncSetAttribute((const void*)attn_v4,
                        hipFuncAttributeMaxDynamicSharedMemorySize, ATTN_LDS);

    // weights -> bf16
    f2bf<<<128, 256, 0, stream>>>(Wq, Wqb, 32768);
    f2bf<<<128, 256, 0, stream>>>(Wk, Wkb, 32768);
    f2bf<<<128, 256, 0, stream>>>(Wv, Wvb, 32768);
    f2bf<<<128, 256, 0, stream>>>(Wp, Wpb, 32768);
    f2bf<<<512, 256, 0, stream>>>(W1, W1b, 131072);
    f2bf<<<512, 256, 0, stream>>>(W2, W2b, 131072);

    ln_kernel<<<NROWS/4, 256, 0, stream>>>(x, gamma, beta, xn_bf);

    dim3 gproj(DIM/128, NROWS/128);
    gemm_bf16<<<gproj, 256, 0, stream>>>(xn_bf, Wqb, nullptr, nullptr, nullptr, Qbf, NROWS, DIM, DIM, 0, 0);
    gemm_bf16<<<gproj, 256, 0, stream>>>(xn_bf, Wkb, nullptr, nullptr, nullptr, Kbf, NROWS, DIM, DIM, 0, 0);
    gemm_bf16<<<gproj, 256, 0, stream>>>(xn_bf, Wvb, nullptr, nullptr, nullptr, att, NROWS, DIM, DIM, 0, 0);
    vtrans<<<dim3(SEQ/64, DIM/64, BATCH), 256, 0, stream>>>(att, Vt);
    // xn_bf/h1 dead -> Opart may overwrite them

    attn_v4<<<256, 512, ATTN_LDS, stream>>>(Qbf, Kbf, Vt, Opart, Mpart, Lpart,
                                            RSQRT_D, nullptr, nullptr, 1);
    attn_merge<<<dim3(64, 2, BATCH), 256, 0, stream>>>(Opart, Mpart, Lpart, att, nullptr,
                                                       nullptr, 1);

    lastrow_scores<<<dim3(SEQ/256, BATCH), 256, 0, stream>>>(Qbf, Kbf, slast);
    entropy_kernel<<<BATCH, 256, 0, stream>>>(slast, Hent);

    // ctx = x + att @ Wp^T   (fp32 into d_out)
    gemm_bf16<<<gproj, 256, 0, stream>>>(att, Wpb, nullptr, x, out, nullptr, NROWS, DIM, DIM, 0, 0);

    // h = LN(ctx) -> xn_bf (Opart dead after merge)
    ln_kernel<<<NROWS/4, 256, 0, stream>>>(out, gamma, beta, xn_bf);

    // FFN: 2 chunks of 4096 rows
    for (int c = 0; c < 2; ++c) {
        const short* hc = xn_bf + (size_t)c * 4096 * DIM;
        float* oc = out + (size_t)c * 4096 * DIM;
        gemm_bf16<<<dim3(FF/128, 4096/128), 256, 0, stream>>>(hc, W1b, b1, nullptr, nullptr, h1,
                                                              4096, FF, DIM, 1, 0);
        gemm_bf16<<<dim3(DIM/128, 4096/128), 256, 0, stream>>>(h1, W2b, b2, nullptr, oc, nullptr,
                                                               4096, DIM, FF, 0, 1);
    }

    krep_partial<<<dim3(64, BATCH), 256, 0, stream>>>(Kbf, kpart);
    scalar_kernel<<<1, 256, 0, stream>>>(Qbf, kpart, Hent, gsc);

    // gated re-attention (non-causal, temperature), accumulate fp32 into out
    attn_v4<<<256, 512, ATTN_LDS, stream>>>(Qbf, Kbf, Vt, Opart, Mpart, Lpart,
                                            0.0f, gsc + 1, gsc, 0);
    attn_merge<<<dim3(64, 2, BATCH), 256, 0, stream>>>(Opart, Mpart, Lpart, nullptr, out,
                                                       gsc, 0);
}

// Round 5
// 412.204 us; speedup vs baseline: 8.9983x; 1.2305x over previous
//
#include <hip/hip_runtime.h>
#include <math.h>

#define BATCH 2
#define SEQ 4096
#define DIM 512
#define FF 2048
#define NROWS (BATCH*SEQ)
#define KT 32
#define RSQRT_D 0.044194173824159216f  /* 1/sqrt(512) */

typedef __attribute__((ext_vector_type(8))) short short8;
typedef __attribute__((ext_vector_type(4))) short short4v;
typedef __attribute__((ext_vector_type(4))) float f32x4;

// ---------------------------------------------------------------- helpers
__device__ __forceinline__ float gelu_f(float v) {
    return 0.5f * v * (1.0f + erff(v * 0.70710678118654752440f));
}
__device__ __forceinline__ short bf16b(float x) {
    union { float f; unsigned u; } c; c.f = x;
    unsigned r = (c.u + 0x7FFFu + ((c.u >> 16) & 1u)) >> 16;
    return (short)r;
}
__device__ __forceinline__ float bf16f(short h) {
    union { unsigned u; float f; } c; c.u = ((unsigned)(unsigned short)h) << 16;
    return c.f;
}
__device__ __forceinline__ void gload16(const void* g, void* l) {
    __builtin_amdgcn_global_load_lds(
        (const __attribute__((address_space(1))) unsigned int*)g,
        (__attribute__((address_space(3))) unsigned int*)l, 16, 0, 0);
}
__device__ __forceinline__ float blk_sum256(float v, volatile float* sm) {
    #pragma unroll
    for (int o = 32; o; o >>= 1) v += __shfl_xor(v, o);
    __syncthreads();
    if ((threadIdx.x & 63) == 0) sm[threadIdx.x >> 6] = v;
    __syncthreads();
    return sm[0] + sm[1] + sm[2] + sm[3];
}

// ---------------------------------------------------------------- all weights f32 -> bf16 (one launch)
__global__ __launch_bounds__(256) void f2bf_all(
        const float* __restrict__ Wq, const float* __restrict__ Wk,
        const float* __restrict__ Wv, const float* __restrict__ Wp,
        const float* __restrict__ W1, const float* __restrict__ W2,
        short* __restrict__ Wcat, short* __restrict__ Wpb,
        short* __restrict__ W1b, short* __restrict__ W2b)
{
    int i = blockIdx.x * 256 + threadIdx.x;    // 8-elem group, total 393216
    const float* src; short* dst; int loc;
    if      (i <  32768) { src = Wq; dst = Wcat;          loc = i; }
    else if (i <  65536) { src = Wk; dst = Wcat + 262144; loc = i - 32768; }
    else if (i <  98304) { src = Wv; dst = Wcat + 524288; loc = i - 65536; }
    else if (i < 131072) { src = Wp; dst = Wpb;           loc = i - 98304; }
    else if (i < 262144) { src = W1; dst = W1b;           loc = i - 131072; }
    else                 { src = W2; dst = W2b;           loc = i - 262144; }
    const float4* p = (const float4*)(src + (size_t)loc * 8);
    float4 a = p[0], b = p[1];
    short8 r;
    r[0]=bf16b(a.x); r[1]=bf16b(a.y); r[2]=bf16b(a.z); r[3]=bf16b(a.w);
    r[4]=bf16b(b.x); r[5]=bf16b(b.y); r[6]=bf16b(b.z); r[7]=bf16b(b.w);
    *(short8*)(dst + (size_t)loc * 8) = r;
}

// ---------------------------------------------------------------- layernorm (f32 in, bf16 out)
__global__ __launch_bounds__(256) void ln_kernel(const float* __restrict__ x,
        const float* __restrict__ g, const float* __restrict__ be,
        short* __restrict__ o)
{
    int row  = blockIdx.x * 4 + (threadIdx.x >> 6);
    int lane = threadIdx.x & 63;
    const float4* xr = (const float4*)(x + (size_t)row * DIM);
    float4 v0 = xr[lane*2], v1 = xr[lane*2+1];
    float s = v0.x+v0.y+v0.z+v0.w + v1.x+v1.y+v1.z+v1.w;
    #pragma unroll
    for (int off = 32; off; off >>= 1) s += __shfl_xor(s, off);
    float mu = s * (1.0f/DIM);
    float d[8] = {v0.x-mu, v0.y-mu, v0.z-mu, v0.w-mu, v1.x-mu, v1.y-mu, v1.z-mu, v1.w-mu};
    float q = 0.f;
    #pragma unroll
    for (int j = 0; j < 8; ++j) q += d[j]*d[j];
    #pragma unroll
    for (int off = 32; off; off >>= 1) q += __shfl_xor(q, off);
    float rs = rsqrtf(q * (1.0f/DIM) + 1e-5f);
    const float4* g4 = (const float4*)g;
    const float4* b4 = (const float4*)be;
    float4 ga = g4[lane*2], gb = g4[lane*2+1];
    float4 ba = b4[lane*2], bb = b4[lane*2+1];
    float gv[8] = {ga.x,ga.y,ga.z,ga.w, gb.x,gb.y,gb.z,gb.w};
    float bv[8] = {ba.x,ba.y,ba.z,ba.w, bb.x,bb.y,bb.z,bb.w};
    short8 r;
    #pragma unroll
    for (int j = 0; j < 8; ++j) r[j] = bf16b(d[j]*rs*gv[j] + bv[j]);
    *(short8*)(o + (size_t)row * DIM + lane*8) = r;
}

// ---------------------------------------------------------------- bf16 MFMA GEMM v2
// C[M,N] = A[M,K] (stride sa) * W[N,K]^T (stride sw), 128x128 tile, BK=32,
// 256 thr, double-buffered LDS, T3 2-phase (prefetch before compute, one barrier).
// Outputs: Cf fp32 (stride sc, opt accum) and/or Cb bf16; QKV mode when CbK!=null
// (cols 0-511 -> Cb, 512-1023 -> CbK, 1024-1535 -> CbV, each stride 512).
__global__ __launch_bounds__(256) void gemm_v2(
        const short* __restrict__ A, const short* __restrict__ W,
        const float* __restrict__ bias, const float* __restrict__ res,
        float* __restrict__ Cf, short* __restrict__ Cb,
        short* __restrict__ CbK, short* __restrict__ CbV,
        int K, int sa, int sw, int sc, int act, int accum)
{
    __shared__ short As[2][4096];
    __shared__ short Ws[2][4096];
    int tid = threadIdx.x;
    int m0 = blockIdx.y * 128, n0 = blockIdx.x * 128;
    int w = tid >> 6, lane = tid & 63;
    int wr = (w >> 1) * 64, wc = (w & 1) * 64;
    int lr = lane & 15, lg = lane >> 4;
    int srow = tid >> 2, skoff = (tid & 3) * 8;
    const short* Ab = A + (size_t)(m0 + srow) * sa + skoff;
    const short* Wb = W + (size_t)(n0 + srow) * sw + skoff;

    #define STAGE_G(buf, kk) do { \
        gload16(Ab + (kk),                    As[buf] + tid*8); \
        gload16(Ab + (size_t)64*sa + (kk),    As[buf] + 2048 + tid*8); \
        gload16(Wb + (kk),                    Ws[buf] + tid*8); \
        gload16(Wb + (size_t)64*sw + (kk),    Ws[buf] + 2048 + tid*8); } while(0)

    f32x4 acc[4][4];
    f32x4 zero = {0.f, 0.f, 0.f, 0.f};
    #pragma unroll
    for (int i = 0; i < 4; ++i)
        #pragma unroll
        for (int j = 0; j < 4; ++j) acc[i][j] = zero;

    STAGE_G(0, 0);
    __syncthreads();
    int cur = 0;
    for (int k0 = 0; k0 < K; k0 += 32) {
        if (k0 + 32 < K) STAGE_G(cur ^ 1, k0 + 32);
        short8 a[4], b[4];
        #pragma unroll
        for (int i = 0; i < 4; ++i) a[i] = *(const short8*)(As[cur] + (wr + i*16 + lr)*32 + lg*8);
        #pragma unroll
        for (int j = 0; j < 4; ++j) b[j] = *(const short8*)(Ws[cur] + (wc + j*16 + lr)*32 + lg*8);
        #pragma unroll
        for (int i = 0; i < 4; ++i)
            #pragma unroll
            for (int j = 0; j < 4; ++j)
                acc[i][j] = __builtin_amdgcn_mfma_f32_16x16x32_bf16(a[i], b[j], acc[i][j], 0, 0, 0);
        __syncthreads();      // drains prefetch (vmcnt0) + LDS reads done
        cur ^= 1;
    }
    #undef STAGE_G

    #pragma unroll
    for (int i = 0; i < 4; ++i) {
        #pragma unroll
        for (int r = 0; r < 4; ++r) {
            size_t m = (size_t)m0 + wr + i*16 + lg*4 + r;
            #pragma unroll
            for (int j = 0; j < 4; ++j) {
                int n = n0 + wc + j*16 + lr;
                float v = acc[i][j][r];
                if (bias) v += bias[n];
                if (act)  v = gelu_f(v);
                if (CbK) {                    // QKV routing mode
                    int seg = n >> 9, nl = n & 511;
                    short* dst = (seg == 0) ? Cb : (seg == 1) ? CbK : CbV;
                    dst[m * 512 + nl] = bf16b(v);
                } else {
                    if (res) v += res[m * sc + n];
                    size_t idx = m * sc + n;
                    if (Cf) { if (accum) Cf[idx] += v; else Cf[idx] = v; }
                    if (Cb) Cb[idx] = bf16b(v);
                }
            }
        }
    }
}

// ---------------------------------------------------------------- bf16 tile transpose V[b][l][d] -> Vt[b][d][l]
__global__ __launch_bounds__(256) void vtrans(const short* __restrict__ V,
                                              short* __restrict__ Vt)
{
    __shared__ short t_s[64][72];
    int l0 = blockIdx.x * 64, d0 = blockIdx.y * 64, b = blockIdx.z;
    int t = threadIdx.x;
    const short* src = V + (size_t)b * SEQ * DIM;
    #pragma unroll
    for (int it = 0; it < 2; ++it) {
        int r = (t >> 3) + it * 32, c = (t & 7) * 8;
        *(short8*)&t_s[r][c] = *(const short8*)(src + (size_t)(l0 + r) * DIM + d0 + c);
    }
    __syncthreads();
    short* dst = Vt + (size_t)b * DIM * SEQ;
    #pragma unroll
    for (int it = 0; it < 2; ++it) {
        int r = (t >> 3) + it * 32, c = (t & 7) * 8;
        short8 v;
        #pragma unroll
        for (int j = 0; j < 8; ++j) v[j] = t_s[c + j][r];
        *(short8*)(dst + (size_t)(d0 + r) * SEQ + l0 + c) = v;
    }
}

// ---------------------------------------------------------------- attention v4 (unchanged from r4)
__global__ __launch_bounds__(512, 2) void attn_v4(
        const short* __restrict__ Q, const short* __restrict__ K,
        const short* __restrict__ Vt, short* __restrict__ Opart,
        float* __restrict__ Mpart, float* __restrict__ Lpart,
        float scale, const float* __restrict__ scale_ptr,
        const float* __restrict__ gate, int causal)
{
    if (gate && gate[0] == 0.0f) return;
    if (scale_ptr) scale = scale_ptr[0];
    extern __shared__ short lds[];
    short* k_s = lds;            // [2][32 rows][512 dims]  64 KB
    short* v_s = lds + 32768;    // [2][512 d][32 keys]     64 KB (swizzled slots)
    short* p_s = lds + 65536;    // [8 waves][16 rows][32]   8 KB

    int tid = threadIdx.x, w = tid >> 6, lane = tid & 63;
    int rg = w >> 1, dh = w & 1;
    int lr = lane & 15, lg = lane >> 4;

    int bid = blockIdx.x;
    int cb = bid & 7;
    int c  = cb & 3, b = cb >> 2;
    int ip = bid >> 3;
    int jj0 = ip, jj1 = 63 - ip;
    int TA = causal ? 2*(ip+1)  : 128;
    int TB = causal ? 2*(64-ip) : 128;
    int Ttot = TA + TB;
    int s0 = (Ttot * c) >> 2, s1 = (Ttot * (c+1)) >> 2;

    size_t bofs = (size_t)b * SEQ * DIM;
    size_t vofs = (size_t)b * DIM * SEQ;
    f32x4 zero = {0.f, 0.f, 0.f, 0.f};

    for (int sg = 0; sg < 2; ++sg) {
        int j  = sg ? jj1 : jj0;
        int ta = sg ? (max(s0, TA) - TA) : s0;
        int tb = sg ? (s1 - TA)          : min(s1, TA);
        if (ta >= tb) continue;
        int qw0 = j*64 + rg*16;

        short8 qf[16];
        #pragma unroll
        for (int kc = 0; kc < 16; ++kc)
            qf[kc] = *(const short8*)(Q + bofs + (size_t)(qw0 + lr)*DIM + kc*32 + lg*8);

        f32x4 o[16];
        #pragma unroll
        for (int df = 0; df < 16; ++df) o[df] = zero;
        float mreg[4] = {-1e30f,-1e30f,-1e30f,-1e30f};
        float lreg[4] = {0.f,0.f,0.f,0.f};
        int rowg[4];
        #pragma unroll
        for (int r = 0; r < 4; ++r) rowg[r] = qw0 + lg*4 + r;

        int cur = 0;
        {
            int k0s = ta * KT;
            #pragma unroll
            for (int s4 = 0; s4 < 4; ++s4) {
                int slot = tid + s4*512;
                int row = slot >> 6, cg = slot & 63;
                gload16(K + bofs + (size_t)(k0s + row)*DIM + ((cg ^ (row & 7)) << 3),
                        k_s + slot*8);
                int dpair = slot >> 3, low = slot & 7;
                int d = dpair*2 + (low & 1);
                int kg = (low >> 1) ^ (dpair & 3);
                gload16(Vt + vofs + (size_t)d*SEQ + k0s + kg*8,
                        v_s + slot*8);
            }
        }
        __syncthreads();

        for (int t = ta; t < tb; ++t) {
            int k0 = t * KT;
            if (t + 1 < tb) {
                int k0s = (t + 1) * KT;
                int bo = (cur ^ 1) * 16384;
                #pragma unroll
                for (int s4 = 0; s4 < 4; ++s4) {
                    int slot = tid + s4*512;
                    int row = slot >> 6, cg = slot & 63;
                    gload16(K + bofs + (size_t)(k0s + row)*DIM + ((cg ^ (row & 7)) << 3),
                            k_s + bo + slot*8);
                    int dpair = slot >> 3, low = slot & 7;
                    int d = dpair*2 + (low & 1);
                    int kg = (low >> 1) ^ (dpair & 3);
                    gload16(Vt + vofs + (size_t)d*SEQ + k0s + kg*8,
                            v_s + bo + slot*8);
                }
            }
            f32x4 ss[2];
            ss[0] = zero; ss[1] = zero;
            const short* kb = k_s + cur*16384;
            #pragma unroll
            for (int kc = 0; kc < 16; ++kc) {
                #pragma unroll
                for (int kf = 0; kf < 2; ++kf) {
                    int row = kf*16 + lr;
                    short8 kk = *(const short8*)(kb + row*512 + (((kc*4 + lg) ^ (row & 7)) << 3));
                    ss[kf] = __builtin_amdgcn_mfma_f32_16x16x32_bf16(qf[kc], kk, ss[kf], 0, 0, 0);
                }
            }
            bool needmask = causal && (k0 + KT - 1 > qw0);
            #pragma unroll
            for (int kf = 0; kf < 2; ++kf) {
                int key = k0 + kf*16 + lr;
                #pragma unroll
                for (int r = 0; r < 4; ++r) {
                    float sv = ss[kf][r] * scale;
                    if (needmask && key > rowg[r]) sv = -1e30f;
                    ss[kf][r] = sv;
                }
            }
            float pm[4];
            bool tg = false;
            #pragma unroll
            for (int r = 0; r < 4; ++r) {
                pm[r] = fmaxf(ss[0][r], ss[1][r]);
                tg |= (pm[r] > mreg[r]);
            }
            if (__any(tg)) {
                #pragma unroll
                for (int r = 0; r < 4; ++r) {
                    float v = pm[r];
                    v = fmaxf(v, __shfl_xor(v, 1));
                    v = fmaxf(v, __shfl_xor(v, 2));
                    v = fmaxf(v, __shfl_xor(v, 4));
                    v = fmaxf(v, __shfl_xor(v, 8));
                    float nm = fmaxf(mreg[r], v);
                    float fr = __expf(mreg[r] - nm);
                    mreg[r] = nm;
                    lreg[r] *= fr;
                    #pragma unroll
                    for (int df = 0; df < 16; ++df) o[df][r] *= fr;
                }
            }
            #pragma unroll
            for (int kf = 0; kf < 2; ++kf) {
                #pragma unroll
                for (int r = 0; r < 4; ++r) {
                    float sv = ss[kf][r];
                    float p = (sv < -1e29f) ? 0.0f : __expf(sv - mreg[r]);
                    lreg[r] += p;
                    p_s[w*512 + (lg*4 + r)*32 + kf*16 + lr] = bf16b(p);
                }
            }
            short8 pa = *(const short8*)(p_s + w*512 + lr*32 + lg*8);
            const short* vb = v_s + cur*16384;
            #pragma unroll
            for (int df = 0; df < 16; ++df) {
                int d = dh*256 + df*16 + lr;
                int slot16 = (d >> 1)*8 + (((lg ^ ((d >> 1) & 3)) << 1) | (d & 1));
                short8 vv = *(const short8*)(vb + slot16*8);
                o[df] = __builtin_amdgcn_mfma_f32_16x16x32_bf16(pa, vv, o[df], 0, 0, 0);
            }
            __syncthreads();
            cur ^= 1;
        }

        #pragma unroll
        for (int r = 0; r < 4; ++r) {
            float v = lreg[r];
            v += __shfl_xor(v, 1);
            v += __shfl_xor(v, 2);
            v += __shfl_xor(v, 4);
            v += __shfl_xor(v, 8);
            lreg[r] = v;
        }
        int slot = (b*64 + j)*4 + c;
        size_t obase = ((size_t)slot*8 + w) * 4096;
        #pragma unroll
        for (int df = 0; df < 16; ++df) {
            short4v pk;
            #pragma unroll
            for (int r = 0; r < 4; ++r) pk[r] = bf16b(o[df][r]);
            *(short4v*)(Opart + obase + df*256 + lane*4) = pk;
        }
        if (dh == 0 && lr == 0) {
            #pragma unroll
            for (int r = 0; r < 4; ++r) {
                Mpart[slot*64 + rg*16 + lg*4 + r] = mreg[r];
                Lpart[slot*64 + rg*16 + lg*4 + r] = lreg[r];
            }
        }
    }
}

// ---------------------------------------------------------------- merge chunk partials (unchanged)
__global__ __launch_bounds__(256) void attn_merge(
        const short* __restrict__ Opart, const float* __restrict__ Mpart,
        const float* __restrict__ Lpart, short* __restrict__ attb,
        float* __restrict__ outf, const float* __restrict__ gate, int causal)
{
    if (gate && gate[0] == 0.0f) return;
    __shared__ float wts[4][64];
    int j = blockIdx.x, dh = blockIdx.y, b = blockIdx.z;
    int tid = threadIdx.x;
    int ip = (j < 32) ? j : 63 - j;
    int TA = causal ? 2*(ip+1)  : 128;
    int TB = causal ? 2*(64-ip) : 128;
    int Ttot = TA + TB;
    int jstart = (j < 32) ? 0 : TA;
    int jend   = (j < 32) ? TA : Ttot;
    bool val[4];
    #pragma unroll
    for (int c = 0; c < 4; ++c) {
        int sc = (Ttot * c) >> 2, ec = (Ttot * (c+1)) >> 2;
        val[c] = (sc < jend) && (ec > jstart);
    }
    if (tid < 64) {
        float M = -1e30f;
        #pragma unroll
        for (int c = 0; c < 4; ++c)
            if (val[c]) M = fmaxf(M, Mpart[((b*64 + j)*4 + c)*64 + tid]);
        float L = 0.f;
        #pragma unroll
        for (int c = 0; c < 4; ++c)
            if (val[c]) L += Lpart[((b*64 + j)*4 + c)*64 + tid]
                           * __expf(Mpart[((b*64 + j)*4 + c)*64 + tid] - M);
        float invL = 1.0f / L;
        #pragma unroll
        for (int c = 0; c < 4; ++c)
            wts[c][tid] = val[c]
                ? __expf(Mpart[((b*64 + j)*4 + c)*64 + tid] - M) * invL : 0.0f;
    }
    __syncthreads();
    int wv = tid >> 6, lane = tid & 63, lg = lane >> 4, lr = lane & 15;
    int region = wv*2 + dh;
    #pragma unroll 4
    for (int df = 0; df < 16; ++df) {
        float acc[4] = {0.f, 0.f, 0.f, 0.f};
        #pragma unroll
        for (int c = 0; c < 4; ++c) {
            if (!val[c]) continue;
            size_t idx = ((size_t)((b*64 + j)*4 + c)*8 + region)*4096 + df*256 + lane*4;
            short4v v = *(const short4v*)(Opart + idx);
            #pragma unroll
            for (int r = 0; r < 4; ++r)
                acc[r] += wts[c][wv*16 + lg*4 + r] * bf16f(v[r]);
        }
        #pragma unroll
        for (int r = 0; r < 4; ++r) {
            int row = j*64 + wv*16 + lg*4 + r;
            int d = dh*256 + df*16 + lr;
            size_t oidx = (size_t)b*SEQ*DIM + (size_t)row*DIM + d;
            if (attb) attb[oidx] = bf16b(acc[r]);
            else      outf[oidx] += acc[r];
        }
    }
}

// ---------------------------------------------------------------- last-row scores (bf16 in)
__global__ __launch_bounds__(256) void lastrow_scores(const short* __restrict__ Q,
        const short* __restrict__ K, float* __restrict__ slast)
{
    __shared__ float q_l[DIM];
    int b = blockIdx.y;
    int m = blockIdx.x * 256 + threadIdx.x;
    for (int i = threadIdx.x; i < DIM; i += 256)
        q_l[i] = bf16f(Q[((size_t)b*SEQ + SEQ-1)*DIM + i]);
    __syncthreads();
    const short* kr = K + ((size_t)b*SEQ + m) * DIM;
    float s = 0.f;
    for (int d = 0; d < DIM; d += 8) {
        short8 k8 = *(const short8*)(kr + d);
        #pragma unroll
        for (int j = 0; j < 8; ++j) s += q_l[d + j] * bf16f(k8[j]);
    }
    slast[(size_t)b*SEQ + m] = s * RSQRT_D;
}

// ---------------------------------------------------------------- entropy of last-row softmax
__global__ __launch_bounds__(256) void entropy_kernel(const float* __restrict__ slast,
        float* __restrict__ H)
{
    __shared__ float sm[4];
    int b = blockIdx.x, t = threadIdx.x;
    const float* s = slast + (size_t)b * SEQ;
    float v[16];
    float mx = -1e30f;
    #pragma unroll
    for (int j = 0; j < 16; ++j) { v[j] = s[t + j*256]; mx = fmaxf(mx, v[j]); }
    #pragma unroll
    for (int o = 32; o; o >>= 1) mx = fmaxf(mx, __shfl_xor(mx, o));
    __syncthreads();
    if ((t & 63) == 0) sm[t >> 6] = mx;
    __syncthreads();
    mx = fmaxf(fmaxf(sm[0], sm[1]), fmaxf(sm[2], sm[3]));
    float se = 0.f;
    #pragma unroll
    for (int j = 0; j < 16; ++j) { v[j] = expf(v[j] - mx); se += v[j]; }
    se = blk_sum256(se, sm);
    float inv = 1.0f / se;
    float h = 0.f;
    #pragma unroll
    for (int j = 0; j < 16; ++j) {
        float p = fmaxf(v[j] * inv, 1e-9f);
        h -= p * logf(p);
    }
    h = blk_sum256(h, sm);
    if (t == 0) H[b] = h;
}

// ---------------------------------------------------------------- K mean partials (bf16 in)
__global__ __launch_bounds__(256) void krep_partial(const short* __restrict__ K,
        float* __restrict__ part)
{
    int b = blockIdx.y, j = blockIdx.x, t = threadIdx.x;
    size_t base = ((size_t)b*SEQ + (size_t)j*64) * DIM;
    float s0 = 0.f, s1 = 0.f;
    for (int r = 0; r < 64; ++r) {
        s0 += bf16f(K[base + (size_t)r*DIM + t]);
        s1 += bf16f(K[base + (size_t)r*DIM + t + 256]);
    }
    size_t o = (size_t)(b*64 + j) * DIM;
    part[o + t] = s0; part[o + t + 256] = s1;
}

// ---------------------------------------------------------------- gate scalar kernel
__global__ __launch_bounds__(256) void scalar_kernel(const short* __restrict__ Qb,
        const float* __restrict__ part, const float* __restrict__ Hent,
        float* __restrict__ gsc)
{
    __shared__ float sm[4];
    __shared__ float sims[BATCH];
    int t = threadIdx.x;
    float qv0 = 0.5f*(bf16f(Qb[((size_t)0*SEQ + SEQ-1)*DIM + t])     + bf16f(Qb[((size_t)1*SEQ + SEQ-1)*DIM + t]));
    float qv1 = 0.5f*(bf16f(Qb[((size_t)0*SEQ + SEQ-1)*DIM + t+256]) + bf16f(Qb[((size_t)1*SEQ + SEQ-1)*DIM + t+256]));
    for (int b = 0; b < BATCH; ++b) {
        float k0 = 0.f, k1 = 0.f;
        for (int j = 0; j < 64; ++j) {
            k0 += part[(size_t)(b*64+j)*DIM + t];
            k1 += part[(size_t)(b*64+j)*DIM + t + 256];
        }
        k0 *= (1.0f/SEQ); k1 *= (1.0f/SEQ);
        float num = blk_sum256(qv0*k0 + qv1*k1, sm);
        float qq  = blk_sum256(qv0*qv0 + qv1*qv1, sm);
        float kk  = blk_sum256(k0*k0 + k1*k1, sm);
        if (t == 0) {
            float na = fmaxf(sqrtf(qq), 1e-8f);
            float nb = fmaxf(sqrtf(kk), 1e-8f);
            sims[b] = num / (na * nb);
        }
        __syncthreads();
    }
    if (t == 0) {
        float H0 = Hent[0], H1 = Hent[1];
        float mn = fminf(H0, H1), mx = fmaxf(H0, H1);
        float den = (mx - mn) + 1e-9f;
        float Hm = 0.5f*((H0 - mn)/den + (H1 - mn)/den);
        float T  = 0.6f + (1.6f - 0.6f) * Hm;
        float th = 0.9f - (0.9f - 0.5f) * Hm;
        float s  = 0.5f * (sims[0] + sims[1]);
        gsc[0] = (s >= th) ? 1.0f : 0.0f;
        gsc[1] = 1.0f / (sqrtf((float)DIM) * T);
    }
}

// ---------------------------------------------------------------- launch
extern "C" void kernel_launch(void* const* d_in, const int* in_sizes, int n_in,
                              void* d_out, int out_size, void* d_ws, size_t ws_size,
                              hipStream_t stream)
{
    (void)in_sizes; (void)n_in; (void)out_size; (void)ws_size;
    const float* x     = (const float*)d_in[0];
    const float* Wq    = (const float*)d_in[1];
    const float* Wk    = (const float*)d_in[2];
    const float* Wv    = (const float*)d_in[3];
    const float* Wp    = (const float*)d_in[4];
    const float* W1    = (const float*)d_in[5];
    const float* b1    = (const float*)d_in[6];
    const float* W2    = (const float*)d_in[7];
    const float* b2    = (const float*)d_in[8];
    const float* gamma = (const float*)d_in[9];
    const float* beta  = (const float*)d_in[10];
    float* out = (float*)d_out;

    const size_t NT = (size_t)NROWS * DIM;   // 4,194,304
    short* bws   = (short*)d_ws;
    short* Qbf   = bws;                      // 4M
    short* Kbf   = Qbf + NT;                 // 4M
    short* Vt    = Kbf + NT;                 // 4M
    short* att   = Vt + NT;                  // 4M (also V pre-transpose temp)
    short* Wcat  = att + NT;                 // 786432 (Wq|Wk|Wv rows)
    short* Wpb   = Wcat + 786432;
    short* W1b   = Wpb + 262144;
    short* W2b   = W1b + 1048576;
    float* slast = (float*)(W2b + 1048576);  // 8192
    float* Hent  = slast + 8192;             // 8
    float* kpart = Hent + 8;                 // 65536
    float* gsc   = kpart + 65536;            // 8
    float* Mpart = gsc + 8;                  // 32768
    float* Lpart = Mpart + 32768;            // 32768
    short* xn_bf = (short*)(Lpart + 32768);  // 4M (dead during attention)
    short* h1    = xn_bf + NT;               // 8M ([8192][1024] FFN half)
    short* Opart = xn_bf;                    // 16.8M shorts: xn(4M)+h1(8M)+spare

    const int ATTN_LDS = 139264;
    hipFuncSetAttribute((const void*)attn_v4,
                        hipFuncAttributeMaxDynamicSharedMemorySize, ATTN_LDS);

    f2bf_all<<<1536, 256, 0, stream>>>(Wq, Wk, Wv, Wp, W1, W2, Wcat, Wpb, W1b, W2b);

    ln_kernel<<<NROWS/4, 256, 0, stream>>>(x, gamma, beta, xn_bf);

    // fused QKV projection: [8192,512] x [1536,512]^T, routed outputs
    gemm_v2<<<dim3(1536/128, NROWS/128), 256, 0, stream>>>(
        xn_bf, Wcat, nullptr, nullptr, nullptr, Qbf, Kbf, att,
        DIM, DIM, DIM, DIM, 0, 0);
    vtrans<<<dim3(SEQ/64, DIM/64, BATCH), 256, 0, stream>>>(att, Vt);
    // xn_bf/h1 dead -> Opart may overwrite them

    attn_v4<<<256, 512, ATTN_LDS, stream>>>(Qbf, Kbf, Vt, Opart, Mpart, Lpart,
                                            RSQRT_D, nullptr, nullptr, 1);
    attn_merge<<<dim3(64, 2, BATCH), 256, 0, stream>>>(Opart, Mpart, Lpart, att, nullptr,
                                                       nullptr, 1);

    lastrow_scores<<<dim3(SEQ/256, BATCH), 256, 0, stream>>>(Qbf, Kbf, slast);
    entropy_kernel<<<BATCH, 256, 0, stream>>>(slast, Hent);

    // ctx = x + att @ Wp^T (fp32 into d_out)
    gemm_v2<<<dim3(DIM/128, NROWS/128), 256, 0, stream>>>(
        att, Wpb, nullptr, x, out, nullptr, nullptr, nullptr,
        DIM, DIM, DIM, DIM, 0, 0);

    // h = LN(ctx) -> xn_bf (Opart dead after merge)
    ln_kernel<<<NROWS/4, 256, 0, stream>>>(out, gamma, beta, xn_bf);

    // FFN: chunk along F (2 x 1024 cols), W2 as split-K accumulation
    for (int c = 0; c < 2; ++c) {
        // h1[8192][1024] = gelu(xn @ W1[1024c..]^T + b1[1024c..])
        gemm_v2<<<dim3(1024/128, NROWS/128), 256, 0, stream>>>(
            xn_bf, W1b + (size_t)c*1024*DIM, b1 + c*1024, nullptr,
            nullptr, h1, nullptr, nullptr,
            DIM, DIM, DIM, 1024, 1, 0);
        // out += h1 @ W2[:, 1024c..]^T (+ b2 on first chunk)
        gemm_v2<<<dim3(DIM/128, NROWS/128), 256, 0, stream>>>(
            h1, W2b + (size_t)c*1024, (c == 0) ? b2 : nullptr, nullptr,
            out, nullptr, nullptr, nullptr,
            1024, 1024, FF, DIM, 0, 1);
    }

    krep_partial<<<dim3(64, BATCH), 256, 0, stream>>>(Kbf, kpart);
    scalar_kernel<<<1, 256, 0, stream>>>(Qbf, kpart, Hent, gsc);

    // gated re-attention (non-causal, temperature), accumulate fp32 into out
    attn_v4<<<256, 512, ATTN_LDS, stream>>>(Qbf, Kbf, Vt, Opart, Mpart, Lpart,
                                            0.0f, gsc + 1, gsc, 0);
    attn_merge<<<dim3(64, 2, BATCH), 256, 0, stream>>>(Opart, Mpart, Lpart, nullptr, out,
                                                       gsc, 0);
}